// Round 4
// baseline (463.597 us; speedup 1.0000x reference)
//
#include <hip/hip_runtime.h>

typedef __bf16 bf16;
typedef __bf16 bf16x2 __attribute__((ext_vector_type(2)));
typedef __bf16 bf16x4 __attribute__((ext_vector_type(4)));
typedef __bf16 bf16x8 __attribute__((ext_vector_type(8)));
typedef float f32x4 __attribute__((ext_vector_type(4)));
typedef float f32x16 __attribute__((ext_vector_type(16)));

#define MFMA_BF16(a, b, c) __builtin_amdgcn_mfma_f32_16x16x32_bf16(a, b, c, 0, 0, 0)
#define MFMA32(a, b, c)    __builtin_amdgcn_mfma_f32_32x32x16_bf16(a, b, c, 0, 0, 0)

__device__ __forceinline__ void async16(const void* g, void* l) {
    __builtin_amdgcn_global_load_lds(
        (const __attribute__((address_space(1))) void*)g,
        (__attribute__((address_space(3))) void*)l,
        16, 0, 0);
}

__device__ __forceinline__ unsigned pack2(float a, float b) {
    bf16x2 t; t[0] = (bf16)a; t[1] = (bf16)b;
    return __builtin_bit_cast(unsigned, t);
}

// ---------------- prep: all fp32->bf16 converts + RoPE tables + mask, ONE dispatch ----------------
__device__ __forceinline__ void cvt8_body(const float* __restrict__ in,
                                          bf16* __restrict__ out, int blk) {
    int i = (blk * 256 + (int)threadIdx.x) * 8;
    float4 a = *(const float4*)(in + i);
    float4 b = *(const float4*)(in + i + 4);
    bf16x8 o;
    o[0] = (bf16)a.x; o[1] = (bf16)a.y; o[2] = (bf16)a.z; o[3] = (bf16)a.w;
    o[4] = (bf16)b.x; o[5] = (bf16)b.y; o[6] = (bf16)b.z; o[7] = (bf16)b.w;
    *(bf16x8*)(out + i) = o;
}

__global__ void prep(const float* __restrict__ x, const float* __restrict__ qkvw,
                     const float* __restrict__ outw, const int* __restrict__ am,
                     bf16* __restrict__ xb, bf16* __restrict__ wqkv, bf16* __restrict__ wout,
                     float* __restrict__ cosT, float* __restrict__ sinT,
                     float* __restrict__ mbias) {
    int blk = blockIdx.x;
    if (blk < 4096)        cvt8_body(x,    xb,   blk);
    else if (blk < 10240)  cvt8_body(qkvw, wqkv, blk - 4096);
    else if (blk < 12288)  cvt8_body(outw, wout, blk - 10240);
    else {
        int i = (blk - 12288) * 256 + threadIdx.x;   // 0 .. 2048*128-1
        int s = i >> 7, d = i & 127, fi = d & 63;
        float inv = exp2f(-(float)fi * (13.287712379549449f / 64.0f));
        float ang = (float)s * inv;
        cosT[i] = cosf(ang);
        sinT[i] = sinf(ang);
        if (i < 2 * 2048) mbias[i] = (am[i] == 0) ? -1.4427e30f : 0.0f;  // exp2 domain
    }
}

// ---------------- QKV GEMM 256x256, BK=32, 3-slot rotating LDS, counted vmcnt ----------------
// C[4096,6144] = A[4096,2048] @ Bt[6144,2048]^T + bias, fused RoPE/scatter epilogue
// (identical math to gemm_bt<1>'s epilogue).
// 512 thr = 8 waves (2M x 4N), wave tile 128x64: per K-step/wave 12 ds_read_b128
// feed 32 MFMA (0.375 reads/MFMA -> LDS pipe ~= matrix pipe, balanced).
// LDS: 3 slots x (A 16KB + B 16KB) = 96 KB. Stage k-step t+2 into the slot freed
// at t-1 (barrier(t-1) guarantees all waves done reading), compute slot t, then
// s_waitcnt vmcnt(4) + ONE barrier: slot t+1's 4 loads retired, t+2's stay in
// flight across the barrier. vmcnt(0) only at the tail -> no per-step drain.
// LDS slot layout (folded, 128-B rows = full bank sweep, m97-verified geometry):
//   global (row r in [0,256), kcol k' in [0,32)) lives at
//   [r & 127][ k' + 32*(r>>7) ], 8-elem chunk index XOR-swizzled by (r & 7).
// NOTE: NO lambdas touching acc (round-1 lesson: lambda capture spilled the
// 128-VGPR accumulator to scratch -> VGPR_Count 92, 2.7x slowdown).
__global__ void __launch_bounds__(512, 2)
qkv256(const bf16* __restrict__ A, const bf16* __restrict__ Bt,
       const float* __restrict__ bias,
       bf16* __restrict__ qb, bf16* __restrict__ kb, bf16* __restrict__ vtb,
       const float* __restrict__ cosT, const float* __restrict__ sinT) {
    constexpr int K = 2048, NT = K >> 5;   // 64 K-steps
    __shared__ __align__(16) bf16 sA[3][8192];
    __shared__ __align__(16) bf16 sB[3][8192];
    const int tid  = threadIdx.x;
    const int lane = tid & 63;
    const int quad = lane >> 4, l15 = lane & 15;
    const int wid  = tid >> 6, wm = wid >> 2, wn = wid & 3;
    const int bm = blockIdx.x, bn = blockIdx.y;

    f32x4 acc[8][4];
#pragma unroll
    for (int i = 0; i < 8; i++)
#pragma unroll
        for (int j = 0; j < 4; j++)
#pragma unroll
            for (int c = 0; c < 4; c++) acc[i][j][c] = 0.0f;

    // ---- staging map: thread covers LDS elems (j*512+tid)*8, j in {0,1}, per operand.
    // LDS (lr, chunk sc): lr = j*64 + (tid>>3), sc = tid&7.
    // Inverse swizzle: u = sc ^ (lr&7) -> hi = u>>2 (row fold), kc = u&3 (k chunk).
    const int trow = tid >> 3;                     // 0..63
    const int u    = (tid & 7) ^ (trow & 7);       // j*64 doesn't affect &7
    const int hi   = u >> 2, kc = u & 3;
    const bf16* pA0 = A  + (size_t)(bm * 256 +      trow + 128 * hi) * K + kc * 8;
    const bf16* pA1 = A  + (size_t)(bm * 256 + 64 + trow + 128 * hi) * K + kc * 8;
    const bf16* pB0 = Bt + (size_t)(bn * 256 +      trow + 128 * hi) * K + kc * 8;
    const bf16* pB1 = Bt + (size_t)(bn * 256 + 64 + trow + 128 * hi) * K + kc * 8;
    const int ld0 = tid * 8, ld1 = 4096 + tid * 8;

    bf16 *cA = sA[0], *nA = sA[1], *fA = sA[2];
    bf16 *cB = sB[0], *nB = sB[1], *fB = sB[2];

#define STAGE(DA, DB) do {                                   \
        async16(pA0, (DA) + ld0); async16(pA1, (DA) + ld1);  \
        async16(pB0, (DB) + ld0); async16(pB1, (DB) + ld1);  \
        pA0 += 32; pA1 += 32; pB0 += 32; pB1 += 32;          \
    } while (0)

    // ---- fragment read offsets (k-chunk = quad; conflict-free: distinct chunk
    // per consecutive-8-lane group, rows 128-B aligned, 2-way alias free)
    const int xa = ((quad + 4 * wm) ^ (l15 & 7)) * 8;          // A: hi = wm
    const int xb = ((quad + 4 * (wn >> 1)) ^ (l15 & 7)) * 8;   // B: hi = wn>>1
    const int ra = l15;                                        // + mi*16
    const int rb = (wn & 1) * 64 + l15;                        // + ni*16

    // ---- prologue: slots 0,1 in flight; publish slot 0 (slot 1's 4 loads remain)
    STAGE(cA, cB);
    STAGE(nA, nB);
    asm volatile("s_waitcnt vmcnt(4)" ::: "memory");
    __builtin_amdgcn_sched_barrier(0);
    __builtin_amdgcn_s_barrier();
    __builtin_amdgcn_sched_barrier(0);

#pragma unroll 1
    for (int t = 0; t < NT; ++t) {
        if (t + 2 < NT) STAGE(fA, fB);        // into slot freed at t-1
        {
            bf16x8 af[8], bv[4];
#pragma unroll
            for (int mi = 0; mi < 8; mi++)
                af[mi] = *(const bf16x8*)(cA + (mi * 16 + ra) * 64 + xa);
#pragma unroll
            for (int ni = 0; ni < 4; ni++)
                bv[ni] = *(const bf16x8*)(cB + (ni * 16 + rb) * 64 + xb);
#pragma unroll
            for (int mi = 0; mi < 8; mi++)
#pragma unroll
                for (int ni = 0; ni < 4; ni++)
                    acc[mi][ni] = MFMA_BF16(af[mi], bv[ni], acc[mi][ni]);
        }
        __builtin_amdgcn_sched_barrier(0);
        if (t + 1 < NT) {
            if (t + 2 < NT) asm volatile("s_waitcnt vmcnt(4)" ::: "memory");
            else            asm volatile("s_waitcnt vmcnt(0)" ::: "memory");
            __builtin_amdgcn_sched_barrier(0);
            __builtin_amdgcn_s_barrier();     // publish slot t+1; free slot t
            __builtin_amdgcn_sched_barrier(0);
        }
        bf16* tp;
        tp = cA; cA = nA; nA = fA; fA = tp;
        tp = cB; cB = nB; nB = fB; fB = tp;
    }
#undef STAGE

    // ---- epilogue: bias + RoPE + q-scale + scatter to q/k/v^T (same math as gemm_bt<1>)
#pragma unroll
    for (int mi = 0; mi < 8; mi++)
#pragma unroll
        for (int ni = 0; ni < 4; ni++) {
            int col   = bn * 256 + wn * 64 + ni * 16 + l15;
            int which = col >> 11;
            int hcol  = col & 2047;
            int h = hcol >> 7, d = hcol & 127;
            float bv = bias[col];
#pragma unroll
            for (int r = 0; r < 4; r++) {
                int row = bm * 256 + wm * 128 + mi * 16 + quad * 4 + r;
                int b = row >> 11, s = row & 2047;
                float v  = acc[mi][ni][r] + bv;
                float vp = __shfl_xor(v, 1, 64);   // partner column d^1
                float ov = v;
                if (which < 2) {
                    float c  = cosT[(s << 7) + d];
                    float sn = sinT[(s << 7) + d];
                    ov = v * c + ((d & 1) ? vp : -vp) * sn;
                }
                // q pre-scale: 1/sqrt(128)/ln2 (exp2-domain softmax)
                if (which == 0) ov *= 0.12751743f;
                size_t bh = (size_t)(b * 16 + h);
                if (which == 0)      qb[(bh * 2048 + s) * 128 + d] = (bf16)ov;
                else if (which == 1) kb[(bh * 2048 + s) * 128 + d] = (bf16)ov;
                else                 vtb[(bh * 128 + d) * 2048 + s] = (bf16)ov;
            }
        }
}

// ---------------- GEMM: C[M,N] = A[M,K] @ Bt[N,K]^T + bias ----------------
// (m97-structure; proven. Kept for gemm2 — also serves as the in-run clock
// reference against qkv256 in the per-dispatch profile.)
template <int EPI>
__global__ void __launch_bounds__(256, 2)
gemm_bt(const bf16* __restrict__ A, const bf16* __restrict__ Bt,
        const float* __restrict__ bias, float* __restrict__ Cf,
        bf16* __restrict__ qb, bf16* __restrict__ kb, bf16* __restrict__ vtb,
        const float* __restrict__ cosT, const float* __restrict__ sinT,
        int M, int N, int K) {
    __shared__ __align__(16) bf16 sA[128 * 64];
    __shared__ __align__(16) bf16 sB[128 * 64];
    const int tid  = threadIdx.x;
    const int lane = tid & 63;
    const int quad = lane >> 4, l15 = lane & 15;
    const int wid = tid >> 6, wm = wid >> 1, wn = wid & 1;
    const int bm = blockIdx.x, bn = blockIdx.y;

    f32x4 acc[4][4];
#pragma unroll
    for (int i = 0; i < 4; i++)
#pragma unroll
        for (int j = 0; j < 4; j++)
#pragma unroll
            for (int c = 0; c < 4; c++) acc[i][j][c] = 0.0f;

    const int r0 = tid >> 3, x0 = tid & 7;
    const int g0 = x0 ^ (r0 & 7);
    const bf16* pa = A  + (size_t)(bm * 128 + r0) * K + g0 * 8;
    const bf16* pb = Bt + (size_t)(bn * 128 + r0) * K + g0 * 8;
    bf16* la = sA + tid * 8;
    bf16* lb = sB + tid * 8;
    const size_t gstep = (size_t)32 * K;

    for (int k0 = 0; k0 < K; k0 += 64) {
#pragma unroll
        for (int i = 0; i < 4; i++) {
            async16(pa + i * gstep, la + i * 2048);
            async16(pb + i * gstep, lb + i * 2048);
        }
        pa += 64; pb += 64;
        __syncthreads();
#pragma unroll
        for (int ks = 0; ks < 2; ks++) {
            bf16x8 af[4], bfr[4];
#pragma unroll
            for (int i = 0; i < 4; i++) {
                int r = wm * 64 + i * 16 + l15;
                int x = (ks * 4 + quad) ^ (r & 7);
                af[i] = *(const bf16x8*)(sA + r * 64 + x * 8);
            }
#pragma unroll
            for (int i = 0; i < 4; i++) {
                int r = wn * 64 + i * 16 + l15;
                int x = (ks * 4 + quad) ^ (r & 7);
                bfr[i] = *(const bf16x8*)(sB + r * 64 + x * 8);
            }
#pragma unroll
            for (int mi = 0; mi < 4; mi++)
#pragma unroll
                for (int ni = 0; ni < 4; ni++)
                    acc[mi][ni] = MFMA_BF16(af[mi], bfr[ni], acc[mi][ni]);
        }
        __syncthreads();
    }

    if (EPI == 0) {
#pragma unroll
        for (int mi = 0; mi < 4; mi++)
#pragma unroll
            for (int ni = 0; ni < 4; ni++) {
                int row0 = bm * 128 + wm * 64 + mi * 16 + quad * 4;
                int col  = bn * 128 + wn * 64 + ni * 16 + l15;
                float bv = bias[col];
#pragma unroll
                for (int r = 0; r < 4; r++)
                    Cf[(size_t)(row0 + r) * N + col] = acc[mi][ni][r] + bv;
            }
    } else {
#pragma unroll
        for (int mi = 0; mi < 4; mi++)
#pragma unroll
            for (int ni = 0; ni < 4; ni++) {
                int col   = bn * 128 + wn * 64 + ni * 16 + l15;
                int which = col >> 11;
                int hcol  = col & 2047;
                int h = hcol >> 7, d = hcol & 127;
                float bv = bias[col];
#pragma unroll
                for (int r = 0; r < 4; r++) {
                    int row = bm * 128 + wm * 64 + mi * 16 + quad * 4 + r;
                    int b = row >> 11, s = row & 2047;
                    float v  = acc[mi][ni][r] + bv;
                    float vp = __shfl_xor(v, 1, 64);
                    float ov = v;
                    if (which < 2) {
                        float c  = cosT[(s << 7) + d];
                        float sn = sinT[(s << 7) + d];
                        ov = v * c + ((d & 1) ? vp : -vp) * sn;
                    }
                    if (which == 0) ov *= 0.12751743f;
                    size_t bh = (size_t)(b * 16 + h);
                    if (which == 0)      qb[(bh * 2048 + s) * 128 + d] = (bf16)ov;
                    else if (which == 1) kb[(bh * 2048 + s) * 128 + d] = (bf16)ov;
                    else                 vtb[(bh * 128 + d) * 2048 + s] = (bf16)ov;
                }
            }
    }
}

// ---------------- Flash attention v7: split-K + setprio + defer-max + LDS mbias ----------------
// Grid 512 1-D: id -> bh = id&31, v = id>>5, p = v>>1, role = v&1.
// (All 16 blocks of a given bh share raw%8 -> per-bh K/V already co-locates
//  on one XCD under round-robin dispatch.)
// Pair (heavy qt a=15-p [nkt=32-2p], light qt p [nkt=2p+2]); 34 tiles split:
//   role 0: qt=a, tiles [0,17)            -> partial slot (bh,a,0)
//   role 1: qt=a, tiles [17,32-2p)        -> partial slot (bh,a,1)
//           then qt=p, tiles [0,2p+2)     -> direct write (normalized)
// Partials: unnormalized O^T (fp32) + (m,l) per q-row; merged by combine().
__global__ void __launch_bounds__(256, 2)
fattn(const bf16* __restrict__ Q, const bf16* __restrict__ Kg,
      const bf16* __restrict__ Vt, const float* __restrict__ mbias,
      bf16* __restrict__ O, float* __restrict__ Opart, float* __restrict__ mlpart) {
    __shared__ __align__(16) bf16 sK[2][64 * 128];   // [buf][key][d]
    __shared__ __align__(16) bf16 sV[2][128 * 64];   // [buf][d][key]
    __shared__ __align__(16) float sMB[2048];        // mask bias row (8 KB)
    const int tid = threadIdx.x, lane = tid & 63, w = tid >> 6;
    const int l31 = lane & 31, half = lane >> 5;
    const int id = (int)blockIdx.x;
    const int bh = id & 31, v = id >> 5;
    const int p = v >> 1, role = v & 1;
    const int qa = 15 - p;                 // heavy q-tile
    const int n1 = role ? (15 - 2 * p) : 17;   // first-segment tile count

    const bf16* Qb  = Q  + (size_t)bh * 2048 * 128;
    const bf16* Kbh = Kg + (size_t)bh * 2048 * 128;
    const bf16* Vbh = Vt + (size_t)bh * 128 * 2048;
    const int b = bh >> 4, hh = bh & 15;
    const float* mbb = mbias + b * 2048;

    // per-lane read swizzles (full-bank coverage)
    const int swk = (l31 & 15) ^ (l31 >> 4);
    const int swv = (l31 & 7) ^ ((l31 >> 3) & 3);
    // staging indices
    const int rk = tid >> 4, xk = tid & 15, gkb = xk ^ rk;   // ^ (i&1) per i
    const int rv = tid >> 3, xv = tid & 7;
    const int gv = xv ^ (rv & 7) ^ ((rv >> 3) & 3);

    // tile t in [0,17) -> key-tile index
    auto KT = [&](int t) { return role ? (t < n1 ? 17 + t : t - n1) : t; };

    int qt = qa;
    int myq  = qt * 128 + w * 32 + l31;
    int qmin = qt * 128 + w * 32;

    bf16x8 qf[8];
#pragma unroll
    for (int kq = 0; kq < 8; kq++)
        qf[kq] = *(const bf16x8*)(Qb + (size_t)myq * 128 + kq * 16 + half * 8);

    f32x16 oacc[4];
#pragma unroll
    for (int dt = 0; dt < 4; dt++)
#pragma unroll
        for (int c = 0; c < 16; c++) oacc[dt][c] = 0.0f;
    float m_s = -3e38f, l_s = 0.0f;

    // hoist mask-bias row to LDS
    {
        float4 t0 = *(const float4*)(mbb + tid * 8);
        float4 t1 = *(const float4*)(mbb + tid * 8 + 4);
        *(float4*)(sMB + tid * 8) = t0;
        *(float4*)(sMB + tid * 8 + 4) = t1;
    }

    // stage tile 0 into buffer 0
    {
        int kb0 = KT(0) * 64;
#pragma unroll
        for (int i = 0; i < 4; i++) {
            async16(Kbh + (size_t)(kb0 + rk + i * 16) * 128 + (gkb ^ (i & 1)) * 8,
                    &sK[0][(i * 256 + tid) * 8]);
            async16(Vbh + (size_t)(rv + i * 32) * 2048 + kb0 + gv * 8,
                    &sV[0][(i * 256 + tid) * 8]);
        }
    }
    __syncthreads();

    for (int t = 0; t < 17; t++) {
        // segment boundary (role 1 only): finalize heavy partial, switch to light qt
        if (role && t == n1) {
            float lf = l_s + __shfl_xor(l_s, 32, 64);
            size_t slot = (size_t)(bh * 8 + (qa - 8)) * 2 + 1;
            float* op = Opart + slot * 16384 + (size_t)(w * 32 + l31) * 128;
#pragma unroll
            for (int dt = 0; dt < 4; dt++)
#pragma unroll
                for (int g = 0; g < 4; g++) {
                    float4 o4 = make_float4(oacc[dt][g * 4 + 0], oacc[dt][g * 4 + 1],
                                            oacc[dt][g * 4 + 2], oacc[dt][g * 4 + 3]);
                    *(float4*)(op + dt * 32 + 8 * g + 4 * half) = o4;
                }
            if (half == 0) {
                float* mp = mlpart + (slot * 128 + (w * 32 + l31)) * 2;
                mp[0] = m_s; mp[1] = lf;
            }
#pragma unroll
            for (int dt = 0; dt < 4; dt++)
#pragma unroll
                for (int c = 0; c < 16; c++) oacc[dt][c] = 0.0f;
            m_s = -3e38f; l_s = 0.0f;
            qt = p;   // light q-tile
            myq  = qt * 128 + w * 32 + l31;
            qmin = qt * 128 + w * 32;
#pragma unroll
            for (int kq = 0; kq < 8; kq++)
                qf[kq] = *(const bf16x8*)(Qb + (size_t)myq * 128 + kq * 16 + half * 8);
        }

        const int kb0 = KT(t) * 64;
        const int buf = t & 1;
        if (t + 1 < 17) {
            const int nb0 = KT(t + 1) * 64;
#pragma unroll
            for (int i = 0; i < 4; i++) {
                async16(Kbh + (size_t)(nb0 + rk + i * 16) * 128 + (gkb ^ (i & 1)) * 8,
                        &sK[buf ^ 1][(i * 256 + tid) * 8]);
                async16(Vbh + (size_t)(rv + i * 32) * 2048 + nb0 + gv * 8,
                        &sV[buf ^ 1][(i * 256 + tid) * 8]);
            }
        }
        const bf16* sKb = sK[buf];
        const bf16* sVb = sV[buf];

        // S^T: rows = keys (2 tiles of 32), col = query
        f32x16 sacc[2];
#pragma unroll
        for (int tt = 0; tt < 2; tt++)
#pragma unroll
            for (int c = 0; c < 16; c++) sacc[tt][c] = 0.0f;
        __builtin_amdgcn_s_setprio(1);
#pragma unroll
        for (int kq = 0; kq < 8; kq++) {
#pragma unroll
            for (int tt = 0; tt < 2; tt++) {
                int row = tt * 32 + l31;
                int x = (kq * 2 + half) ^ swk;
                bf16x8 kf = *(const bf16x8*)(sKb + row * 128 + x * 8);
                sacc[tt] = MFMA32(kf, qf[kq], sacc[tt]);
            }
        }
        __builtin_amdgcn_s_setprio(0);

        // mask in-place (exp2 domain); mask bias from LDS
        float mx = -3e38f;
        if (kb0 + 63 < qmin) {          // interior tile
#pragma unroll
            for (int tt = 0; tt < 2; tt++)
#pragma unroll
                for (int g = 0; g < 4; g++) {
                    float4 mb4 = *(const float4*)(sMB + kb0 + tt * 32 + 8 * g + 4 * half);
#pragma unroll
                    for (int r2 = 0; r2 < 4; r2++) {
                        float vv = sacc[tt][g * 4 + r2] + ((const float*)&mb4)[r2];
                        sacc[tt][g * 4 + r2] = vv;
                        mx = fmaxf(mx, vv);
                    }
                }
        } else {
#pragma unroll
            for (int tt = 0; tt < 2; tt++)
#pragma unroll
                for (int g = 0; g < 4; g++) {
                    float4 mb4 = *(const float4*)(sMB + kb0 + tt * 32 + 8 * g + 4 * half);
#pragma unroll
                    for (int r2 = 0; r2 < 4; r2++) {
                        int sk = kb0 + tt * 32 + 8 * g + 4 * half + r2;
                        float vv = sacc[tt][g * 4 + r2] + ((const float*)&mb4)[r2];
                        vv = (sk > myq) ? -1e30f : vv;
                        sacc[tt][g * 4 + r2] = vv;
                        mx = fmaxf(mx, vv);
                    }
                }
        }

        // online softmax (exp2 domain): 32 in-lane + 1 cross-half shuffle
        mx = fmaxf(mx, __shfl_xor(mx, 32, 64));
        float mnew = fmaxf(m_s, mx);
        // T13 defer-max: skip O-rescale when tile max grew <= 8 (P bounded by 2^8).
        if (__all(mx - m_s <= 8.0f)) mnew = m_s;
        float alpha = exp2f(m_s - mnew);
        float rs = 0.0f;
#pragma unroll
        for (int tt = 0; tt < 2; tt++)
#pragma unroll
            for (int c = 0; c < 16; c++) {
                float pe = exp2f(sacc[tt][c] - mnew);
                sacc[tt][c] = pe;
                rs += pe;
            }
        l_s = l_s * alpha + rs;
        if (mnew > m_s) {
#pragma unroll
            for (int dt = 0; dt < 4; dt++) oacc[dt] *= alpha;
        }
        m_s = mnew;

        // PV: P B-fragments in-register via cross-half dword exchange
#pragma unroll
        for (int tt = 0; tt < 2; tt++) {
            unsigned w8[8];
#pragma unroll
            for (int i = 0; i < 8; i++)
                w8[i] = pack2(sacc[tt][2 * i], sacc[tt][2 * i + 1]);
#pragma unroll
            for (int s2 = 0; s2 < 2; s2++) {
                const int bse = 4 * s2;
                unsigned a0 = half ? w8[bse]     : w8[bse + 2];
                unsigned a1 = half ? w8[bse + 1] : w8[bse + 3];
                unsigned z0 = (unsigned)__shfl_xor((int)a0, 32, 64);
                unsigned z1 = (unsigned)__shfl_xor((int)a1, 32, 64);
                union { unsigned u[4]; bf16x8 vv; } pu;
                pu.u[0] = half ? z0 : w8[bse];
                pu.u[1] = half ? z1 : w8[bse + 1];
                pu.u[2] = half ? w8[bse + 2] : z0;
                pu.u[3] = half ? w8[bse + 3] : z1;
                bf16x8 pf = pu.vv;
                const int c = (tt * 2 + s2) * 2 + half;
                __builtin_amdgcn_s_setprio(1);
#pragma unroll
                for (int dt = 0; dt < 4; dt++) {
                    int row = dt * 32 + l31;
                    int x = c ^ swv;
                    bf16x8 vf = *(const bf16x8*)(sVb + row * 64 + x * 8);
                    oacc[dt] = MFMA32(vf, pf, oacc[dt]);
                }
                __builtin_amdgcn_s_setprio(0);
            }
        }
        __syncthreads();
    }

    // epilogue
    float lf = l_s + __shfl_xor(l_s, 32, 64);
    if (role == 0) {
        size_t slot = (size_t)(bh * 8 + (qa - 8)) * 2 + 0;
        float* op = Opart + slot * 16384 + (size_t)(w * 32 + l31) * 128;
#pragma unroll
        for (int dt = 0; dt < 4; dt++)
#pragma unroll
            for (int g = 0; g < 4; g++) {
                float4 o4 = make_float4(oacc[dt][g * 4 + 0], oacc[dt][g * 4 + 1],
                                        oacc[dt][g * 4 + 2], oacc[dt][g * 4 + 3]);
                *(float4*)(op + dt * 32 + 8 * g + 4 * half) = o4;
            }
        if (half == 0) {
            float* mp = mlpart + (slot * 128 + (w * 32 + l31)) * 2;
            mp[0] = m_s; mp[1] = lf;
        }
    } else {
        float inv = 1.0f / lf;
        size_t base = ((size_t)(b * 2048 + myq)) * 2048 + hh * 128;
#pragma unroll
        for (int dt = 0; dt < 4; dt++)
#pragma unroll
            for (int g = 0; g < 4; g++) {
                bf16x4 o4;
#pragma unroll
                for (int r2 = 0; r2 < 4; r2++) o4[r2] = (bf16)(oacc[dt][g * 4 + r2] * inv);
                *(bf16x4*)(O + base + dt * 32 + 8 * g + 4 * half) = o4;
            }
    }
}

// ---------------- combine: merge split-K partials for heavy q-tiles ----------------
__global__ void combine(const float* __restrict__ Opart, const float* __restrict__ mlpart,
                        bf16* __restrict__ attn) {
    int i = blockIdx.x * 256 + threadIdx.x;     // 1,048,576 quads
    int dq = (i & 31) * 4;
    int row = i >> 5;                            // (bh*8+ai)*128 + qloc
    int qloc = row & 127, ba = row >> 7;
    int ai = ba & 7, bh = ba >> 3;
    const float* mlA = mlpart + ((size_t)(ba * 2 + 0) * 128 + qloc) * 2;
    const float* mlB = mlpart + ((size_t)(ba * 2 + 1) * 128 + qloc) * 2;
    float mA = mlA[0], lA = mlA[1], mB = mlB[0], lB = mlB[1];
    float m = fmaxf(mA, mB);
    float wA = exp2f(mA - m), wB = exp2f(mB - m);
    float inv = 1.0f / (wA * lA + wB * lB);
    float4 oA = *(const float4*)(Opart + (size_t)(ba * 2 + 0) * 16384 + qloc * 128 + dq);
    float4 oB = *(const float4*)(Opart + (size_t)(ba * 2 + 1) * 16384 + qloc * 128 + dq);
    int q = (8 + ai) * 128 + qloc;
    int b = bh >> 4, hh = bh & 15;
    bf16x4 o4;
    o4[0] = (bf16)((wA * oA.x + wB * oB.x) * inv);
    o4[1] = (bf16)((wA * oA.y + wB * oB.y) * inv);
    o4[2] = (bf16)((wA * oA.z + wB * oB.z) * inv);
    o4[3] = (bf16)((wA * oA.w + wB * oB.w) * inv);
    *(bf16x4*)(attn + ((size_t)(b * 2048 + q)) * 2048 + hh * 128 + dq) = o4;
}

extern "C" void kernel_launch(void* const* d_in, const int* in_sizes, int n_in,
                              void* d_out, int out_size, void* d_ws, size_t ws_size,
                              hipStream_t stream) {
    const float* x     = (const float*)d_in[0];
    const int*   am    = (const int*)d_in[1];
    const float* qkvw  = (const float*)d_in[2];
    const float* qkvb  = (const float*)d_in[3];
    const float* outw  = (const float*)d_in[4];
    const float* outb  = (const float*)d_in[5];
    float* out = (float*)d_out;

    char* ws = (char*)d_ws;
    bf16*  xb    = (bf16*)(ws);                          // 16 MB  x bf16
    bf16*  wqkv  = (bf16*)(ws + (16ull << 20));          // 24 MB  qkv_w bf16
    bf16*  wout  = (bf16*)(ws + (40ull << 20));          //  8 MB  out_w bf16
    bf16*  qb    = (bf16*)(ws + (48ull << 20));          // 16 MB  q (pre-scaled /ln2)
    bf16*  kb    = (bf16*)(ws + (64ull << 20));          // 16 MB  k
    bf16*  vtb   = (bf16*)(ws + (80ull << 20));          // 16 MB  v^T
    bf16*  attn  = (bf16*)(ws + (96ull << 20));          // 16 MB  attn [4096,2048]
    float* cosT  = (float*)(ws + (112ull << 20));        //  1 MB
    float* sinT  = (float*)(ws + (113ull << 20));        //  1 MB
    float* mbias = (float*)(ws + (114ull << 20));        // 16 KB
    // split-K partials ALIAS xb/wqkv (dead after gemm1; stream order guarantees safety)
    float* Opart  = (float*)(ws);                        // 32 MB  [32bh][8a][2role][128q][128d]
    float* mlpart = (float*)(ws + (32ull << 20));        // 0.5 MB [.][.][.][128q][m,l]

    prep<<<13312, 256, 0, stream>>>(x, qkvw, outw, am, xb, wqkv, wout, cosT, sinT, mbias);

    qkv256<<<dim3(16, 24), 512, 0, stream>>>(
        xb, wqkv, qkvb, qb, kb, vtb, cosT, sinT);

    fattn<<<dim3(512), 256, 0, stream>>>(qb, kb, vtb, mbias, attn, Opart, mlpart);

    combine<<<4096, 256, 0, stream>>>(Opart, mlpart, attn);

    gemm_bt<0><<<dim3(32, 16), 256, 0, stream>>>(
        attn, wout, outb, out, nullptr, nullptr, nullptr, nullptr, nullptr,
        4096, 2048, 2048);
}

// Round 5
// 425.983 us; speedup vs baseline: 1.0883x; 1.0883x over previous
//
#include <hip/hip_runtime.h>

typedef __bf16 bf16;
typedef __bf16 bf16x2 __attribute__((ext_vector_type(2)));
typedef __bf16 bf16x4 __attribute__((ext_vector_type(4)));
typedef __bf16 bf16x8 __attribute__((ext_vector_type(8)));
typedef float f32x4 __attribute__((ext_vector_type(4)));
typedef float f32x16 __attribute__((ext_vector_type(16)));

#define MFMA_BF16(a, b, c) __builtin_amdgcn_mfma_f32_16x16x32_bf16(a, b, c, 0, 0, 0)
#define MFMA32(a, b, c)    __builtin_amdgcn_mfma_f32_32x32x16_bf16(a, b, c, 0, 0, 0)

__device__ __forceinline__ void async16(const void* g, void* l) {
    __builtin_amdgcn_global_load_lds(
        (const __attribute__((address_space(1))) void*)g,
        (__attribute__((address_space(3))) void*)l,
        16, 0, 0);
}

__device__ __forceinline__ unsigned pack2(float a, float b) {
    bf16x2 t; t[0] = (bf16)a; t[1] = (bf16)b;
    return __builtin_bit_cast(unsigned, t);
}

// ---------------- prep: all fp32->bf16 converts + RoPE tables + mask, ONE dispatch ----------------
__device__ __forceinline__ void cvt8_body(const float* __restrict__ in,
                                          bf16* __restrict__ out, int blk) {
    int i = (blk * 256 + (int)threadIdx.x) * 8;
    float4 a = *(const float4*)(in + i);
    float4 b = *(const float4*)(in + i + 4);
    bf16x8 o;
    o[0] = (bf16)a.x; o[1] = (bf16)a.y; o[2] = (bf16)a.z; o[3] = (bf16)a.w;
    o[4] = (bf16)b.x; o[5] = (bf16)b.y; o[6] = (bf16)b.z; o[7] = (bf16)b.w;
    *(bf16x8*)(out + i) = o;
}

__global__ void prep(const float* __restrict__ x, const float* __restrict__ qkvw,
                     const float* __restrict__ outw, const int* __restrict__ am,
                     bf16* __restrict__ xb, bf16* __restrict__ wqkv, bf16* __restrict__ wout,
                     float* __restrict__ cosT, float* __restrict__ sinT,
                     float* __restrict__ mbias) {
    int blk = blockIdx.x;
    if (blk < 4096)        cvt8_body(x,    xb,   blk);
    else if (blk < 10240)  cvt8_body(qkvw, wqkv, blk - 4096);
    else if (blk < 12288)  cvt8_body(outw, wout, blk - 10240);
    else {
        int i = (blk - 12288) * 256 + threadIdx.x;   // 0 .. 2048*128-1
        int s = i >> 7, d = i & 127, fi = d & 63;
        float inv = exp2f(-(float)fi * (13.287712379549449f / 64.0f));
        float ang = (float)s * inv;
        cosT[i] = cosf(ang);
        sinT[i] = sinf(ang);
        if (i < 2 * 2048) mbias[i] = (am[i] == 0) ? -1.4427e30f : 0.0f;  // exp2 domain
    }
}

// ---------------- QKV GEMM 256x256, 8-phase-density counted-vmcnt pipeline ----------------
// C[4096,6144] = A[4096,2048] @ Bt[6144,2048]^T + bias, fused RoPE/scatter epilogue.
// Geometry validated in r4 (passed, 0 bank conflicts): 512 thr = 8 waves (2M x 4N),
// wave tile 128x64, folded LDS slot [128 rows][64 cols] per operand per BK=32 step,
// chunk-XOR swizzle keyed on (row & 7).
// NEW (r5): m201-faithful phase schedule — per BK=32 step, TWO phases:
//  ph A: {ds_read af0-3+bv0-3 (8xb128) | stage A-half of slot t+3 (2 gload_lds)}
//        -> s_barrier -> lgkmcnt(0)+sched_barrier (rule #18) -> setprio(1) 16 MFMA -> barrier
//  ph B: {ds_read af4-7 (4xb128; bv reused in regs) | stage B-half}
//        -> MFMA mi4-7 -> counted vmcnt(8) -> FINAL barrier (publishes slot t+1)
// 4-slot ring x (A 16KB + B 16KB) = 128 KB; stage depth 3 (loads issued 2+ K-steps
// before their wait). vmcnt counting (in-order retirement): steady 8 outstanding
// (slots t+2,t+3); tail vmcnt(4) at t=NT-3, vmcnt(0) at t=NT-2.
// Barrier density = m201 template (16 per 128-K). Waves cross the post-MFMA barrier
// while MFMAs drain -> next phase's ds/gload issue under them; setprio arbitrates.
__global__ void __launch_bounds__(512, 2)
qkv8p(const bf16* __restrict__ A, const bf16* __restrict__ Bt,
      const float* __restrict__ bias,
      bf16* __restrict__ qb, bf16* __restrict__ kb, bf16* __restrict__ vtb,
      const float* __restrict__ cosT, const float* __restrict__ sinT) {
    constexpr int K = 2048, NT = K >> 5;   // 64 K-steps of BK=32
    __shared__ __align__(16) bf16 sA[4][8192];
    __shared__ __align__(16) bf16 sB[4][8192];
    const int tid  = threadIdx.x;
    const int lane = tid & 63;
    const int quad = lane >> 4, l15 = lane & 15;
    const int wid  = tid >> 6, wm = wid >> 2, wn = wid & 3;
    const int bm = blockIdx.x, bn = blockIdx.y;

    f32x4 acc[8][4];
#pragma unroll
    for (int i = 0; i < 8; i++)
#pragma unroll
        for (int j = 0; j < 4; j++)
#pragma unroll
            for (int c = 0; c < 4; c++) acc[i][j][c] = 0.0f;

    // ---- staging map (r4-validated): thread covers LDS elems (j*512+tid)*8, j in {0,1}.
    // LDS (lr, chunk sc): lr = j*64 + (tid>>3), sc = tid&7; inverse swizzle:
    // u = sc ^ (lr&7) -> hi = u>>2 (row fold), kc = u&3 (k chunk).
    const int trow = tid >> 3;
    const int u    = (tid & 7) ^ (trow & 7);
    const int hi   = u >> 2, kc = u & 3;
    const bf16* pA0 = A  + (size_t)(bm * 256 +      trow + 128 * hi) * K + kc * 8;
    const bf16* pA1 = A  + (size_t)(bm * 256 + 64 + trow + 128 * hi) * K + kc * 8;
    const bf16* pB0 = Bt + (size_t)(bn * 256 +      trow + 128 * hi) * K + kc * 8;
    const bf16* pB1 = Bt + (size_t)(bn * 256 + 64 + trow + 128 * hi) * K + kc * 8;
    const int ld0 = tid * 8, ld1 = 4096 + tid * 8;

    // ---- fragment read offsets (r4-validated, conflict-free)
    const int xa = ((quad + 4 * wm) ^ (l15 & 7)) * 8;          // A: hi = wm
    const int xb = ((quad + 4 * (wn >> 1)) ^ (l15 & 7)) * 8;   // B: hi = wn>>1
    const int ra = l15;                                        // + mi*16
    const int rb = (wn & 1) * 64 + l15;                        // + ni*16

    // ---- prologue: stage slots 0,1,2 (12 loads); wait slot 0 (8 left in flight)
#pragma unroll
    for (int s = 0; s < 3; ++s) {
        async16(pA0, &sA[s][0] + ld0); async16(pA1, &sA[s][0] + ld1);
        pA0 += 32; pA1 += 32;
        async16(pB0, &sB[s][0] + ld0); async16(pB1, &sB[s][0] + ld1);
        pB0 += 32; pB1 += 32;
    }
    __builtin_amdgcn_sched_barrier(0);
    asm volatile("s_waitcnt vmcnt(8)" ::: "memory");
    __builtin_amdgcn_sched_barrier(0);
    __builtin_amdgcn_s_barrier();
    __builtin_amdgcn_sched_barrier(0);

#pragma unroll 1
    for (int t = 0; t < NT; ++t) {
        const bf16* cA = &sA[t & 3][0];
        const bf16* cB = &sB[t & 3][0];
        bf16* gA = &sA[(t + 3) & 3][0];
        bf16* gB = &sB[(t + 3) & 3][0];
        const bool st = (t + 3 < NT);

        // ================= phase A =================
        bf16x8 af[4], bv[4];
#pragma unroll
        for (int i = 0; i < 4; i++)
            af[i] = *(const bf16x8*)(cA + ((i * 16 + ra) << 6) + xa);
#pragma unroll
        for (int i = 0; i < 4; i++)
            bv[i] = *(const bf16x8*)(cB + ((i * 16 + rb) << 6) + xb);
        if (st) { async16(pA0, gA + ld0); async16(pA1, gA + ld1); pA0 += 32; pA1 += 32; }
        __builtin_amdgcn_sched_barrier(0);
        __builtin_amdgcn_s_barrier();
        asm volatile("s_waitcnt lgkmcnt(0)" ::: "memory");
        __builtin_amdgcn_sched_barrier(0);
        __builtin_amdgcn_s_setprio(1);
#pragma unroll
        for (int mi = 0; mi < 4; mi++)
#pragma unroll
            for (int ni = 0; ni < 4; ni++)
                acc[mi][ni] = MFMA_BF16(af[mi], bv[ni], acc[mi][ni]);
        __builtin_amdgcn_s_setprio(0);
        __builtin_amdgcn_sched_barrier(0);
        __builtin_amdgcn_s_barrier();
        __builtin_amdgcn_sched_barrier(0);

        // ================= phase B =================
#pragma unroll
        for (int i = 0; i < 4; i++)
            af[i] = *(const bf16x8*)(cA + (((i + 4) * 16 + ra) << 6) + xa);
        if (st) { async16(pB0, gB + ld0); async16(pB1, gB + ld1); pB0 += 32; pB1 += 32; }
        __builtin_amdgcn_sched_barrier(0);
        __builtin_amdgcn_s_barrier();
        asm volatile("s_waitcnt lgkmcnt(0)" ::: "memory");
        __builtin_amdgcn_sched_barrier(0);
        __builtin_amdgcn_s_setprio(1);
#pragma unroll
        for (int mi = 0; mi < 4; mi++)
#pragma unroll
            for (int ni = 0; ni < 4; ni++)
                acc[mi + 4][ni] = MFMA_BF16(af[mi], bv[ni], acc[mi + 4][ni]);
        __builtin_amdgcn_s_setprio(0);
        __builtin_amdgcn_sched_barrier(0);
        // counted wait: slot t+1 must be retired before the publishing barrier;
        // slots t+2,t+3 (8 loads) stay in flight. Tail drains 4 -> 0.
        if (t < NT - 3)       asm volatile("s_waitcnt vmcnt(8)" ::: "memory");
        else if (t == NT - 3) asm volatile("s_waitcnt vmcnt(4)" ::: "memory");
        else if (t == NT - 2) asm volatile("s_waitcnt vmcnt(0)" ::: "memory");
        __builtin_amdgcn_sched_barrier(0);
        __builtin_amdgcn_s_barrier();     // publishes slot t+1; frees position (t+4)&3
        __builtin_amdgcn_sched_barrier(0);
    }

    // ---- epilogue: bias + RoPE + q-scale + scatter to q/k/v^T (r4-validated)
#pragma unroll
    for (int mi = 0; mi < 8; mi++)
#pragma unroll
        for (int ni = 0; ni < 4; ni++) {
            int col   = bn * 256 + wn * 64 + ni * 16 + l15;
            int which = col >> 11;
            int hcol  = col & 2047;
            int h = hcol >> 7, d = hcol & 127;
            float bv2 = bias[col];
#pragma unroll
            for (int r = 0; r < 4; r++) {
                int row = bm * 256 + wm * 128 + mi * 16 + quad * 4 + r;
                int b = row >> 11, s = row & 2047;
                float v  = acc[mi][ni][r] + bv2;
                float vp = __shfl_xor(v, 1, 64);   // partner column d^1
                float ov = v;
                if (which < 2) {
                    float c  = cosT[(s << 7) + d];
                    float sn = sinT[(s << 7) + d];
                    ov = v * c + ((d & 1) ? vp : -vp) * sn;
                }
                // q pre-scale: 1/sqrt(128)/ln2 (exp2-domain softmax)
                if (which == 0) ov *= 0.12751743f;
                size_t bh = (size_t)(b * 16 + h);
                if (which == 0)      qb[(bh * 2048 + s) * 128 + d] = (bf16)ov;
                else if (which == 1) kb[(bh * 2048 + s) * 128 + d] = (bf16)ov;
                else                 vtb[(bh * 128 + d) * 2048 + s] = (bf16)ov;
            }
        }
}

// ---------------- GEMM: C[M,N] = A[M,K] @ Bt[N,K]^T + bias ----------------
// (m97-structure; proven. gemm2 + in-run clock reference vs qkv8p.)
template <int EPI>
__global__ void __launch_bounds__(256, 2)
gemm_bt(const bf16* __restrict__ A, const bf16* __restrict__ Bt,
        const float* __restrict__ bias, float* __restrict__ Cf,
        bf16* __restrict__ qb, bf16* __restrict__ kb, bf16* __restrict__ vtb,
        const float* __restrict__ cosT, const float* __restrict__ sinT,
        int M, int N, int K) {
    __shared__ __align__(16) bf16 sA[128 * 64];
    __shared__ __align__(16) bf16 sB[128 * 64];
    const int tid  = threadIdx.x;
    const int lane = tid & 63;
    const int quad = lane >> 4, l15 = lane & 15;
    const int wid = tid >> 6, wm = wid >> 1, wn = wid & 1;
    const int bm = blockIdx.x, bn = blockIdx.y;

    f32x4 acc[4][4];
#pragma unroll
    for (int i = 0; i < 4; i++)
#pragma unroll
        for (int j = 0; j < 4; j++)
#pragma unroll
            for (int c = 0; c < 4; c++) acc[i][j][c] = 0.0f;

    const int r0 = tid >> 3, x0 = tid & 7;
    const int g0 = x0 ^ (r0 & 7);
    const bf16* pa = A  + (size_t)(bm * 128 + r0) * K + g0 * 8;
    const bf16* pb = Bt + (size_t)(bn * 128 + r0) * K + g0 * 8;
    bf16* la = sA + tid * 8;
    bf16* lb = sB + tid * 8;
    const size_t gstep = (size_t)32 * K;

    for (int k0 = 0; k0 < K; k0 += 64) {
#pragma unroll
        for (int i = 0; i < 4; i++) {
            async16(pa + i * gstep, la + i * 2048);
            async16(pb + i * gstep, lb + i * 2048);
        }
        pa += 64; pb += 64;
        __syncthreads();
#pragma unroll
        for (int ks = 0; ks < 2; ks++) {
            bf16x8 af[4], bfr[4];
#pragma unroll
            for (int i = 0; i < 4; i++) {
                int r = wm * 64 + i * 16 + l15;
                int x = (ks * 4 + quad) ^ (r & 7);
                af[i] = *(const bf16x8*)(sA + r * 64 + x * 8);
            }
#pragma unroll
            for (int i = 0; i < 4; i++) {
                int r = wn * 64 + i * 16 + l15;
                int x = (ks * 4 + quad) ^ (r & 7);
                bfr[i] = *(const bf16x8*)(sB + r * 64 + x * 8);
            }
#pragma unroll
            for (int mi = 0; mi < 4; mi++)
#pragma unroll
                for (int ni = 0; ni < 4; ni++)
                    acc[mi][ni] = MFMA_BF16(af[mi], bfr[ni], acc[mi][ni]);
        }
        __syncthreads();
    }

    if (EPI == 0) {
#pragma unroll
        for (int mi = 0; mi < 4; mi++)
#pragma unroll
            for (int ni = 0; ni < 4; ni++) {
                int row0 = bm * 128 + wm * 64 + mi * 16 + quad * 4;
                int col  = bn * 128 + wn * 64 + ni * 16 + l15;
                float bv = bias[col];
#pragma unroll
                for (int r = 0; r < 4; r++)
                    Cf[(size_t)(row0 + r) * N + col] = acc[mi][ni][r] + bv;
            }
    } else {
#pragma unroll
        for (int mi = 0; mi < 4; mi++)
#pragma unroll
            for (int ni = 0; ni < 4; ni++) {
                int col   = bn * 128 + wn * 64 + ni * 16 + l15;
                int which = col >> 11;
                int hcol  = col & 2047;
                int h = hcol >> 7, d = hcol & 127;
                float bv = bias[col];
#pragma unroll
                for (int r = 0; r < 4; r++) {
                    int row = bm * 128 + wm * 64 + mi * 16 + quad * 4 + r;
                    int b = row >> 11, s = row & 2047;
                    float v  = acc[mi][ni][r] + bv;
                    float vp = __shfl_xor(v, 1, 64);
                    float ov = v;
                    if (which < 2) {
                        float c  = cosT[(s << 7) + d];
                        float sn = sinT[(s << 7) + d];
                        ov = v * c + ((d & 1) ? vp : -vp) * sn;
                    }
                    if (which == 0) ov *= 0.12751743f;
                    size_t bh = (size_t)(b * 16 + h);
                    if (which == 0)      qb[(bh * 2048 + s) * 128 + d] = (bf16)ov;
                    else if (which == 1) kb[(bh * 2048 + s) * 128 + d] = (bf16)ov;
                    else                 vtb[(bh * 128 + d) * 2048 + s] = (bf16)ov;
                }
            }
    }
}

// ---------------- Flash attention v7: split-K + setprio + defer-max + LDS mbias ----------------
// Grid 512 1-D: id -> bh = id&31, v = id>>5, p = v>>1, role = v&1.
// Pair (heavy qt a=15-p [nkt=32-2p], light qt p [nkt=2p+2]); 34 tiles split:
//   role 0: qt=a, tiles [0,17)            -> partial slot (bh,a,0)
//   role 1: qt=a, tiles [17,32-2p)        -> partial slot (bh,a,1)
//           then qt=p, tiles [0,2p+2)     -> direct write (normalized)
// Partials: unnormalized O^T (fp32) + (m,l) per q-row; merged by combine().
__global__ void __launch_bounds__(256, 2)
fattn(const bf16* __restrict__ Q, const bf16* __restrict__ Kg,
      const bf16* __restrict__ Vt, const float* __restrict__ mbias,
      bf16* __restrict__ O, float* __restrict__ Opart, float* __restrict__ mlpart) {
    __shared__ __align__(16) bf16 sK[2][64 * 128];   // [buf][key][d]
    __shared__ __align__(16) bf16 sV[2][128 * 64];   // [buf][d][key]
    __shared__ __align__(16) float sMB[2048];        // mask bias row (8 KB)
    const int tid = threadIdx.x, lane = tid & 63, w = tid >> 6;
    const int l31 = lane & 31, half = lane >> 5;
    const int id = (int)blockIdx.x;
    const int bh = id & 31, v = id >> 5;
    const int p = v >> 1, role = v & 1;
    const int qa = 15 - p;                 // heavy q-tile
    const int n1 = role ? (15 - 2 * p) : 17;   // first-segment tile count

    const bf16* Qb  = Q  + (size_t)bh * 2048 * 128;
    const bf16* Kbh = Kg + (size_t)bh * 2048 * 128;
    const bf16* Vbh = Vt + (size_t)bh * 128 * 2048;
    const int b = bh >> 4, hh = bh & 15;
    const float* mbb = mbias + b * 2048;

    // per-lane read swizzles (full-bank coverage)
    const int swk = (l31 & 15) ^ (l31 >> 4);
    const int swv = (l31 & 7) ^ ((l31 >> 3) & 3);
    // staging indices
    const int rk = tid >> 4, xk = tid & 15, gkb = xk ^ rk;   // ^ (i&1) per i
    const int rv = tid >> 3, xv = tid & 7;
    const int gv = xv ^ (rv & 7) ^ ((rv >> 3) & 3);

    // tile t in [0,17) -> key-tile index
    auto KT = [&](int t) { return role ? (t < n1 ? 17 + t : t - n1) : t; };

    int qt = qa;
    int myq  = qt * 128 + w * 32 + l31;
    int qmin = qt * 128 + w * 32;

    bf16x8 qf[8];
#pragma unroll
    for (int kq = 0; kq < 8; kq++)
        qf[kq] = *(const bf16x8*)(Qb + (size_t)myq * 128 + kq * 16 + half * 8);

    f32x16 oacc[4];
#pragma unroll
    for (int dt = 0; dt < 4; dt++)
#pragma unroll
        for (int c = 0; c < 16; c++) oacc[dt][c] = 0.0f;
    float m_s = -3e38f, l_s = 0.0f;

    // hoist mask-bias row to LDS
    {
        float4 t0 = *(const float4*)(mbb + tid * 8);
        float4 t1 = *(const float4*)(mbb + tid * 8 + 4);
        *(float4*)(sMB + tid * 8) = t0;
        *(float4*)(sMB + tid * 8 + 4) = t1;
    }

    // stage tile 0 into buffer 0
    {
        int kb0 = KT(0) * 64;
#pragma unroll
        for (int i = 0; i < 4; i++) {
            async16(Kbh + (size_t)(kb0 + rk + i * 16) * 128 + (gkb ^ (i & 1)) * 8,
                    &sK[0][(i * 256 + tid) * 8]);
            async16(Vbh + (size_t)(rv + i * 32) * 2048 + kb0 + gv * 8,
                    &sV[0][(i * 256 + tid) * 8]);
        }
    }
    __syncthreads();

    for (int t = 0; t < 17; t++) {
        // segment boundary (role 1 only): finalize heavy partial, switch to light qt
        if (role && t == n1) {
            float lf = l_s + __shfl_xor(l_s, 32, 64);
            size_t slot = (size_t)(bh * 8 + (qa - 8)) * 2 + 1;
            float* op = Opart + slot * 16384 + (size_t)(w * 32 + l31) * 128;
#pragma unroll
            for (int dt = 0; dt < 4; dt++)
#pragma unroll
                for (int g = 0; g < 4; g++) {
                    float4 o4 = make_float4(oacc[dt][g * 4 + 0], oacc[dt][g * 4 + 1],
                                            oacc[dt][g * 4 + 2], oacc[dt][g * 4 + 3]);
                    *(float4*)(op + dt * 32 + 8 * g + 4 * half) = o4;
                }
            if (half == 0) {
                float* mp = mlpart + (slot * 128 + (w * 32 + l31)) * 2;
                mp[0] = m_s; mp[1] = lf;
            }
#pragma unroll
            for (int dt = 0; dt < 4; dt++)
#pragma unroll
                for (int c = 0; c < 16; c++) oacc[dt][c] = 0.0f;
            m_s = -3e38f; l_s = 0.0f;
            qt = p;   // light q-tile
            myq  = qt * 128 + w * 32 + l31;
            qmin = qt * 128 + w * 32;
#pragma unroll
            for (int kq = 0; kq < 8; kq++)
                qf[kq] = *(const bf16x8*)(Qb + (size_t)myq * 128 + kq * 16 + half * 8);
        }

        const int kb0 = KT(t) * 64;
        const int buf = t & 1;
        if (t + 1 < 17) {
            const int nb0 = KT(t + 1) * 64;
#pragma unroll
            for (int i = 0; i < 4; i++) {
                async16(Kbh + (size_t)(nb0 + rk + i * 16) * 128 + (gkb ^ (i & 1)) * 8,
                        &sK[buf ^ 1][(i * 256 + tid) * 8]);
                async16(Vbh + (size_t)(rv + i * 32) * 2048 + nb0 + gv * 8,
                        &sV[buf ^ 1][(i * 256 + tid) * 8]);
            }
        }
        const bf16* sKb = sK[buf];
        const bf16* sVb = sV[buf];

        // S^T: rows = keys (2 tiles of 32), col = query
        f32x16 sacc[2];
#pragma unroll
        for (int tt = 0; tt < 2; tt++)
#pragma unroll
            for (int c = 0; c < 16; c++) sacc[tt][c] = 0.0f;
        __builtin_amdgcn_s_setprio(1);
#pragma unroll
        for (int kq = 0; kq < 8; kq++) {
#pragma unroll
            for (int tt = 0; tt < 2; tt++) {
                int row = tt * 32 + l31;
                int x = (kq * 2 + half) ^ swk;
                bf16x8 kf = *(const bf16x8*)(sKb + row * 128 + x * 8);
                sacc[tt] = MFMA32(kf, qf[kq], sacc[tt]);
            }
        }
        __builtin_amdgcn_s_setprio(0);

        // mask in-place (exp2 domain); mask bias from LDS
        float mx = -3e38f;
        if (kb0 + 63 < qmin) {          // interior tile
#pragma unroll
            for (int tt = 0; tt < 2; tt++)
#pragma unroll
                for (int g = 0; g < 4; g++) {
                    float4 mb4 = *(const float4*)(sMB + kb0 + tt * 32 + 8 * g + 4 * half);
#pragma unroll
                    for (int r2 = 0; r2 < 4; r2++) {
                        float vv = sacc[tt][g * 4 + r2] + ((const float*)&mb4)[r2];
                        sacc[tt][g * 4 + r2] = vv;
                        mx = fmaxf(mx, vv);
                    }
                }
        } else {
#pragma unroll
            for (int tt = 0; tt < 2; tt++)
#pragma unroll
                for (int g = 0; g < 4; g++) {
                    float4 mb4 = *(const float4*)(sMB + kb0 + tt * 32 + 8 * g + 4 * half);
#pragma unroll
                    for (int r2 = 0; r2 < 4; r2++) {
                        int sk = kb0 + tt * 32 + 8 * g + 4 * half + r2;
                        float vv = sacc[tt][g * 4 + r2] + ((const float*)&mb4)[r2];
                        vv = (sk > myq) ? -1e30f : vv;
                        sacc[tt][g * 4 + r2] = vv;
                        mx = fmaxf(mx, vv);
                    }
                }
        }

        // online softmax (exp2 domain): 32 in-lane + 1 cross-half shuffle
        mx = fmaxf(mx, __shfl_xor(mx, 32, 64));
        float mnew = fmaxf(m_s, mx);
        // T13 defer-max: skip O-rescale when tile max grew <= 8 (P bounded by 2^8).
        if (__all(mx - m_s <= 8.0f)) mnew = m_s;
        float alpha = exp2f(m_s - mnew);
        float rs = 0.0f;
#pragma unroll
        for (int tt = 0; tt < 2; tt++)
#pragma unroll
            for (int c = 0; c < 16; c++) {
                float pe = exp2f(sacc[tt][c] - mnew);
                sacc[tt][c] = pe;
                rs += pe;
            }
        l_s = l_s * alpha + rs;
        if (mnew > m_s) {
#pragma unroll
            for (int dt = 0; dt < 4; dt++) oacc[dt] *= alpha;
        }
        m_s = mnew;

        // PV: P B-fragments in-register via cross-half dword exchange
#pragma unroll
        for (int tt = 0; tt < 2; tt++) {
            unsigned w8[8];
#pragma unroll
            for (int i = 0; i < 8; i++)
                w8[i] = pack2(sacc[tt][2 * i], sacc[tt][2 * i + 1]);
#pragma unroll
            for (int s2 = 0; s2 < 2; s2++) {
                const int bse = 4 * s2;
                unsigned a0 = half ? w8[bse]     : w8[bse + 2];
                unsigned a1 = half ? w8[bse + 1] : w8[bse + 3];
                unsigned z0 = (unsigned)__shfl_xor((int)a0, 32, 64);
                unsigned z1 = (unsigned)__shfl_xor((int)a1, 32, 64);
                union { unsigned u[4]; bf16x8 vv; } pu;
                pu.u[0] = half ? z0 : w8[bse];
                pu.u[1] = half ? z1 : w8[bse + 1];
                pu.u[2] = half ? w8[bse + 2] : z0;
                pu.u[3] = half ? w8[bse + 3] : z1;
                bf16x8 pf = pu.vv;
                const int c = (tt * 2 + s2) * 2 + half;
                __builtin_amdgcn_s_setprio(1);
#pragma unroll
                for (int dt = 0; dt < 4; dt++) {
                    int row = dt * 32 + l31;
                    int x = c ^ swv;
                    bf16x8 vf = *(const bf16x8*)(sVb + row * 64 + x * 8);
                    oacc[dt] = MFMA32(vf, pf, oacc[dt]);
                }
                __builtin_amdgcn_s_setprio(0);
            }
        }
        __syncthreads();
    }

    // epilogue
    float lf = l_s + __shfl_xor(l_s, 32, 64);
    if (role == 0) {
        size_t slot = (size_t)(bh * 8 + (qa - 8)) * 2 + 0;
        float* op = Opart + slot * 16384 + (size_t)(w * 32 + l31) * 128;
#pragma unroll
        for (int dt = 0; dt < 4; dt++)
#pragma unroll
            for (int g = 0; g < 4; g++) {
                float4 o4 = make_float4(oacc[dt][g * 4 + 0], oacc[dt][g * 4 + 1],
                                        oacc[dt][g * 4 + 2], oacc[dt][g * 4 + 3]);
                *(float4*)(op + dt * 32 + 8 * g + 4 * half) = o4;
            }
        if (half == 0) {
            float* mp = mlpart + (slot * 128 + (w * 32 + l31)) * 2;
            mp[0] = m_s; mp[1] = lf;
        }
    } else {
        float inv = 1.0f / lf;
        size_t base = ((size_t)(b * 2048 + myq)) * 2048 + hh * 128;
#pragma unroll
        for (int dt = 0; dt < 4; dt++)
#pragma unroll
            for (int g = 0; g < 4; g++) {
                bf16x4 o4;
#pragma unroll
                for (int r2 = 0; r2 < 4; r2++) o4[r2] = (bf16)(oacc[dt][g * 4 + r2] * inv);
                *(bf16x4*)(O + base + dt * 32 + 8 * g + 4 * half) = o4;
            }
    }
}

// ---------------- combine: merge split-K partials for heavy q-tiles ----------------
__global__ void combine(const float* __restrict__ Opart, const float* __restrict__ mlpart,
                        bf16* __restrict__ attn) {
    int i = blockIdx.x * 256 + threadIdx.x;     // 1,048,576 quads
    int dq = (i & 31) * 4;
    int row = i >> 5;                            // (bh*8+ai)*128 + qloc
    int qloc = row & 127, ba = row >> 7;
    int ai = ba & 7, bh = ba >> 3;
    const float* mlA = mlpart + ((size_t)(ba * 2 + 0) * 128 + qloc) * 2;
    const float* mlB = mlpart + ((size_t)(ba * 2 + 1) * 128 + qloc) * 2;
    float mA = mlA[0], lA = mlA[1], mB = mlB[0], lB = mlB[1];
    float m = fmaxf(mA, mB);
    float wA = exp2f(mA - m), wB = exp2f(mB - m);
    float inv = 1.0f / (wA * lA + wB * lB);
    float4 oA = *(const float4*)(Opart + (size_t)(ba * 2 + 0) * 16384 + qloc * 128 + dq);
    float4 oB = *(const float4*)(Opart + (size_t)(ba * 2 + 1) * 16384 + qloc * 128 + dq);
    int q = (8 + ai) * 128 + qloc;
    int b = bh >> 4, hh = bh & 15;
    bf16x4 o4;
    o4[0] = (bf16)((wA * oA.x + wB * oB.x) * inv);
    o4[1] = (bf16)((wA * oA.y + wB * oB.y) * inv);
    o4[2] = (bf16)((wA * oA.z + wB * oB.z) * inv);
    o4[3] = (bf16)((wA * oA.w + wB * oB.w) * inv);
    *(bf16x4*)(attn + ((size_t)(b * 2048 + q)) * 2048 + hh * 128 + dq) = o4;
}

extern "C" void kernel_launch(void* const* d_in, const int* in_sizes, int n_in,
                              void* d_out, int out_size, void* d_ws, size_t ws_size,
                              hipStream_t stream) {
    const float* x     = (const float*)d_in[0];
    const int*   am    = (const int*)d_in[1];
    const float* qkvw  = (const float*)d_in[2];
    const float* qkvb  = (const float*)d_in[3];
    const float* outw  = (const float*)d_in[4];
    const float* outb  = (const float*)d_in[5];
    float* out = (float*)d_out;

    char* ws = (char*)d_ws;
    bf16*  xb    = (bf16*)(ws);                          // 16 MB  x bf16
    bf16*  wqkv  = (bf16*)(ws + (16ull << 20));          // 24 MB  qkv_w bf16
    bf16*  wout  = (bf16*)(ws + (40ull << 20));          //  8 MB  out_w bf16
    bf16*  qb    = (bf16*)(ws + (48ull << 20));          // 16 MB  q (pre-scaled /ln2)
    bf16*  kb    = (bf16*)(ws + (64ull << 20));          // 16 MB  k
    bf16*  vtb   = (bf16*)(ws + (80ull << 20));          // 16 MB  v^T
    bf16*  attn  = (bf16*)(ws + (96ull << 20));          // 16 MB  attn [4096,2048]
    float* cosT  = (float*)(ws + (112ull << 20));        //  1 MB
    float* sinT  = (float*)(ws + (113ull << 20));        //  1 MB
    float* mbias = (float*)(ws + (114ull << 20));        // 16 KB
    // split-K partials ALIAS xb/wqkv (dead after gemm1; stream order guarantees safety)
    float* Opart  = (float*)(ws);                        // 32 MB  [32bh][8a][2role][128q][128d]
    float* mlpart = (float*)(ws + (32ull << 20));        // 0.5 MB [.][.][.][128q][m,l]

    prep<<<13312, 256, 0, stream>>>(x, qkvw, outw, am, xb, wqkv, wout, cosT, sinT, mbias);

    qkv8p<<<dim3(16, 24), 512, 0, stream>>>(
        xb, wqkv, qkvb, qb, kb, vtb, cosT, sinT);

    fattn<<<dim3(512), 256, 0, stream>>>(qb, kb, vtb, mbias, attn, Opart, mlpart);

    combine<<<4096, 256, 0, stream>>>(Opart, mlpart, attn);

    gemm_bt<0><<<dim3(32, 16), 256, 0, stream>>>(
        attn, wout, outb, out, nullptr, nullptr, nullptr, nullptr, nullptr,
        4096, 2048, 2048);
}

// Round 6
// 387.039 us; speedup vs baseline: 1.1978x; 1.1006x over previous
//
#include <hip/hip_runtime.h>

typedef __bf16 bf16;
typedef __bf16 bf16x2 __attribute__((ext_vector_type(2)));
typedef __bf16 bf16x4 __attribute__((ext_vector_type(4)));
typedef __bf16 bf16x8 __attribute__((ext_vector_type(8)));
typedef float f32x4 __attribute__((ext_vector_type(4)));
typedef float f32x16 __attribute__((ext_vector_type(16)));

#define MFMA_BF16(a, b, c) __builtin_amdgcn_mfma_f32_16x16x32_bf16(a, b, c, 0, 0, 0)
#define MFMA32(a, b, c)    __builtin_amdgcn_mfma_f32_32x32x16_bf16(a, b, c, 0, 0, 0)

__device__ __forceinline__ void async16(const void* g, void* l) {
    __builtin_amdgcn_global_load_lds(
        (const __attribute__((address_space(1))) void*)g,
        (__attribute__((address_space(3))) void*)l,
        16, 0, 0);
}

__device__ __forceinline__ unsigned pack2(float a, float b) {
    bf16x2 t; t[0] = (bf16)a; t[1] = (bf16)b;
    return __builtin_bit_cast(unsigned, t);
}

// ---------------- prep: all fp32->bf16 converts + RoPE tables + mask, ONE dispatch ----------------
__device__ __forceinline__ void cvt8_body(const float* __restrict__ in,
                                          bf16* __restrict__ out, int blk) {
    int i = (blk * 256 + (int)threadIdx.x) * 8;
    float4 a = *(const float4*)(in + i);
    float4 b = *(const float4*)(in + i + 4);
    bf16x8 o;
    o[0] = (bf16)a.x; o[1] = (bf16)a.y; o[2] = (bf16)a.z; o[3] = (bf16)a.w;
    o[4] = (bf16)b.x; o[5] = (bf16)b.y; o[6] = (bf16)b.z; o[7] = (bf16)b.w;
    *(bf16x8*)(out + i) = o;
}

__global__ void prep(const float* __restrict__ x, const float* __restrict__ qkvw,
                     const float* __restrict__ outw, const int* __restrict__ am,
                     bf16* __restrict__ xb, bf16* __restrict__ wqkv, bf16* __restrict__ wout,
                     float* __restrict__ cosT, float* __restrict__ sinT,
                     float* __restrict__ mbias) {
    int blk = blockIdx.x;
    if (blk < 4096)        cvt8_body(x,    xb,   blk);
    else if (blk < 10240)  cvt8_body(qkvw, wqkv, blk - 4096);
    else if (blk < 12288)  cvt8_body(outw, wout, blk - 10240);
    else {
        int i = (blk - 12288) * 256 + threadIdx.x;   // 0 .. 2048*128-1
        int s = i >> 7, d = i & 127, fi = d & 63;
        float inv = exp2f(-(float)fi * (13.287712379549449f / 64.0f));
        float ang = (float)s * inv;
        cosT[i] = cosf(ang);
        sinT[i] = sinf(ang);
        if (i < 2 * 2048) mbias[i] = (am[i] == 0) ? -1.4427e30f : 0.0f;  // exp2 domain
    }
}

// ---------------- GEMM: C[M,N] = A[M,K] @ Bt[N,K]^T + bias ----------------
// (m97-structure, 821 TF measured round 0 on this problem; proven — do not touch.
//  256^2 restructure attempts r1/r4/r5 all landed at 455-553 TF: the deep-pipeline
//  regime needs race-screened scheduling we can't iterate headlessly. Closed.)
template <int EPI>
__global__ void __launch_bounds__(256, 2)
gemm_bt(const bf16* __restrict__ A, const bf16* __restrict__ Bt,
        const float* __restrict__ bias, float* __restrict__ Cf,
        bf16* __restrict__ qb, bf16* __restrict__ kb, bf16* __restrict__ vtb,
        const float* __restrict__ cosT, const float* __restrict__ sinT,
        int M, int N, int K) {
    __shared__ __align__(16) bf16 sA[128 * 64];
    __shared__ __align__(16) bf16 sB[128 * 64];
    const int tid  = threadIdx.x;
    const int lane = tid & 63;
    const int quad = lane >> 4, l15 = lane & 15;
    const int wid = tid >> 6, wm = wid >> 1, wn = wid & 1;
    const int bm = blockIdx.x, bn = blockIdx.y;

    f32x4 acc[4][4];
#pragma unroll
    for (int i = 0; i < 4; i++)
#pragma unroll
        for (int j = 0; j < 4; j++)
#pragma unroll
            for (int c = 0; c < 4; c++) acc[i][j][c] = 0.0f;

    const int r0 = tid >> 3, x0 = tid & 7;
    const int g0 = x0 ^ (r0 & 7);
    const bf16* pa = A  + (size_t)(bm * 128 + r0) * K + g0 * 8;
    const bf16* pb = Bt + (size_t)(bn * 128 + r0) * K + g0 * 8;
    bf16* la = sA + tid * 8;
    bf16* lb = sB + tid * 8;
    const size_t gstep = (size_t)32 * K;

    for (int k0 = 0; k0 < K; k0 += 64) {
#pragma unroll
        for (int i = 0; i < 4; i++) {
            async16(pa + i * gstep, la + i * 2048);
            async16(pb + i * gstep, lb + i * 2048);
        }
        pa += 64; pb += 64;
        __syncthreads();
#pragma unroll
        for (int ks = 0; ks < 2; ks++) {
            bf16x8 af[4], bfr[4];
#pragma unroll
            for (int i = 0; i < 4; i++) {
                int r = wm * 64 + i * 16 + l15;
                int x = (ks * 4 + quad) ^ (r & 7);
                af[i] = *(const bf16x8*)(sA + r * 64 + x * 8);
            }
#pragma unroll
            for (int i = 0; i < 4; i++) {
                int r = wn * 64 + i * 16 + l15;
                int x = (ks * 4 + quad) ^ (r & 7);
                bfr[i] = *(const bf16x8*)(sB + r * 64 + x * 8);
            }
#pragma unroll
            for (int mi = 0; mi < 4; mi++)
#pragma unroll
                for (int ni = 0; ni < 4; ni++)
                    acc[mi][ni] = MFMA_BF16(af[mi], bfr[ni], acc[mi][ni]);
        }
        __syncthreads();
    }

    if (EPI == 0) {
#pragma unroll
        for (int mi = 0; mi < 4; mi++)
#pragma unroll
            for (int ni = 0; ni < 4; ni++) {
                int row0 = bm * 128 + wm * 64 + mi * 16 + quad * 4;
                int col  = bn * 128 + wn * 64 + ni * 16 + l15;
                float bv = bias[col];
#pragma unroll
                for (int r = 0; r < 4; r++)
                    Cf[(size_t)(row0 + r) * N + col] = acc[mi][ni][r] + bv;
            }
    } else {
#pragma unroll
        for (int mi = 0; mi < 4; mi++)
#pragma unroll
            for (int ni = 0; ni < 4; ni++) {
                int col   = bn * 128 + wn * 64 + ni * 16 + l15;
                int which = col >> 11;
                int hcol  = col & 2047;
                int h = hcol >> 7, d = hcol & 127;
                float bv = bias[col];
#pragma unroll
                for (int r = 0; r < 4; r++) {
                    int row = bm * 128 + wm * 64 + mi * 16 + quad * 4 + r;
                    int b = row >> 11, s = row & 2047;
                    float v  = acc[mi][ni][r] + bv;
                    float vp = __shfl_xor(v, 1, 64);   // partner column d^1
                    float ov = v;
                    if (which < 2) {
                        float c  = cosT[(s << 7) + d];
                        float sn = sinT[(s << 7) + d];
                        ov = v * c + ((d & 1) ? vp : -vp) * sn;
                    }
                    // q pre-scale: 1/sqrt(128)/ln2 (exp2-domain softmax)
                    if (which == 0) ov *= 0.12751743f;
                    size_t bh = (size_t)(b * 16 + h);
                    if (which == 0)      qb[(bh * 2048 + s) * 128 + d] = (bf16)ov;
                    else if (which == 1) kb[(bh * 2048 + s) * 128 + d] = (bf16)ov;
                    else                 vtb[(bh * 128 + d) * 2048 + s] = (bf16)ov;
                }
            }
    }
}

// ---------------- Flash attention v8: v7 + tree-ILP softmax reductions ----------------
// Grid 512 1-D: id -> bh = id&31, v = id>>5, p = v>>1, role = v&1.
// Pair (heavy qt a=15-p [nkt=32-2p], light qt p [nkt=2p+2]); 34 tiles split:
//   role 0: qt=a, tiles [0,17)            -> partial slot (bh,a,0)
//   role 1: qt=a, tiles [17,32-2p)        -> partial slot (bh,a,1)
//           then qt=p, tiles [0,2p+2)     -> direct write (normalized)
// v8 change: the per-tile max-reduce and sum-reduce were 32-deep serial dependency
// chains (~256 cyc of pure latency on the QK->PV critical path). Both are now
// 4-way-partial trees (depth ~10). Pure reassociation; fp-exact for max.
__global__ void __launch_bounds__(256, 2)
fattn(const bf16* __restrict__ Q, const bf16* __restrict__ Kg,
      const bf16* __restrict__ Vt, const float* __restrict__ mbias,
      bf16* __restrict__ O, float* __restrict__ Opart, float* __restrict__ mlpart) {
    __shared__ __align__(16) bf16 sK[2][64 * 128];   // [buf][key][d]
    __shared__ __align__(16) bf16 sV[2][128 * 64];   // [buf][d][key]
    __shared__ __align__(16) float sMB[2048];        // mask bias row (8 KB)
    const int tid = threadIdx.x, lane = tid & 63, w = tid >> 6;
    const int l31 = lane & 31, half = lane >> 5;
    const int id = (int)blockIdx.x;
    const int bh = id & 31, v = id >> 5;
    const int p = v >> 1, role = v & 1;
    const int qa = 15 - p;                 // heavy q-tile
    const int n1 = role ? (15 - 2 * p) : 17;   // first-segment tile count

    const bf16* Qb  = Q  + (size_t)bh * 2048 * 128;
    const bf16* Kbh = Kg + (size_t)bh * 2048 * 128;
    const bf16* Vbh = Vt + (size_t)bh * 128 * 2048;
    const int b = bh >> 4, hh = bh & 15;
    const float* mbb = mbias + b * 2048;

    // per-lane read swizzles (full-bank coverage)
    const int swk = (l31 & 15) ^ (l31 >> 4);
    const int swv = (l31 & 7) ^ ((l31 >> 3) & 3);
    // staging indices
    const int rk = tid >> 4, xk = tid & 15, gkb = xk ^ rk;   // ^ (i&1) per i
    const int rv = tid >> 3, xv = tid & 7;
    const int gv = xv ^ (rv & 7) ^ ((rv >> 3) & 3);

    // tile t in [0,17) -> key-tile index
    auto KT = [&](int t) { return role ? (t < n1 ? 17 + t : t - n1) : t; };

    int qt = qa;
    int myq  = qt * 128 + w * 32 + l31;
    int qmin = qt * 128 + w * 32;

    bf16x8 qf[8];
#pragma unroll
    for (int kq = 0; kq < 8; kq++)
        qf[kq] = *(const bf16x8*)(Qb + (size_t)myq * 128 + kq * 16 + half * 8);

    f32x16 oacc[4];
#pragma unroll
    for (int dt = 0; dt < 4; dt++)
#pragma unroll
        for (int c = 0; c < 16; c++) oacc[dt][c] = 0.0f;
    float m_s = -3e38f, l_s = 0.0f;

    // hoist mask-bias row to LDS
    {
        float4 t0 = *(const float4*)(mbb + tid * 8);
        float4 t1 = *(const float4*)(mbb + tid * 8 + 4);
        *(float4*)(sMB + tid * 8) = t0;
        *(float4*)(sMB + tid * 8 + 4) = t1;
    }

    // stage tile 0 into buffer 0
    {
        int kb0 = KT(0) * 64;
#pragma unroll
        for (int i = 0; i < 4; i++) {
            async16(Kbh + (size_t)(kb0 + rk + i * 16) * 128 + (gkb ^ (i & 1)) * 8,
                    &sK[0][(i * 256 + tid) * 8]);
            async16(Vbh + (size_t)(rv + i * 32) * 2048 + kb0 + gv * 8,
                    &sV[0][(i * 256 + tid) * 8]);
        }
    }
    __syncthreads();

    for (int t = 0; t < 17; t++) {
        // segment boundary (role 1 only): finalize heavy partial, switch to light qt
        if (role && t == n1) {
            float lf = l_s + __shfl_xor(l_s, 32, 64);
            size_t slot = (size_t)(bh * 8 + (qa - 8)) * 2 + 1;
            float* op = Opart + slot * 16384 + (size_t)(w * 32 + l31) * 128;
#pragma unroll
            for (int dt = 0; dt < 4; dt++)
#pragma unroll
                for (int g = 0; g < 4; g++) {
                    float4 o4 = make_float4(oacc[dt][g * 4 + 0], oacc[dt][g * 4 + 1],
                                            oacc[dt][g * 4 + 2], oacc[dt][g * 4 + 3]);
                    *(float4*)(op + dt * 32 + 8 * g + 4 * half) = o4;
                }
            if (half == 0) {
                float* mp = mlpart + (slot * 128 + (w * 32 + l31)) * 2;
                mp[0] = m_s; mp[1] = lf;
            }
#pragma unroll
            for (int dt = 0; dt < 4; dt++)
#pragma unroll
                for (int c = 0; c < 16; c++) oacc[dt][c] = 0.0f;
            m_s = -3e38f; l_s = 0.0f;
            qt = p;   // light q-tile
            myq  = qt * 128 + w * 32 + l31;
            qmin = qt * 128 + w * 32;
#pragma unroll
            for (int kq = 0; kq < 8; kq++)
                qf[kq] = *(const bf16x8*)(Qb + (size_t)myq * 128 + kq * 16 + half * 8);
        }

        const int kb0 = KT(t) * 64;
        const int buf = t & 1;
        if (t + 1 < 17) {
            const int nb0 = KT(t + 1) * 64;
#pragma unroll
            for (int i = 0; i < 4; i++) {
                async16(Kbh + (size_t)(nb0 + rk + i * 16) * 128 + (gkb ^ (i & 1)) * 8,
                        &sK[buf ^ 1][(i * 256 + tid) * 8]);
                async16(Vbh + (size_t)(rv + i * 32) * 2048 + nb0 + gv * 8,
                        &sV[buf ^ 1][(i * 256 + tid) * 8]);
            }
        }
        const bf16* sKb = sK[buf];
        const bf16* sVb = sV[buf];

        // S^T: rows = keys (2 tiles of 32), col = query
        f32x16 sacc[2];
#pragma unroll
        for (int tt = 0; tt < 2; tt++)
#pragma unroll
            for (int c = 0; c < 16; c++) sacc[tt][c] = 0.0f;
        __builtin_amdgcn_s_setprio(1);
#pragma unroll
        for (int kq = 0; kq < 8; kq++) {
#pragma unroll
            for (int tt = 0; tt < 2; tt++) {
                int row = tt * 32 + l31;
                int x = (kq * 2 + half) ^ swk;
                bf16x8 kf = *(const bf16x8*)(sKb + row * 128 + x * 8);
                sacc[tt] = MFMA32(kf, qf[kq], sacc[tt]);
            }
        }
        __builtin_amdgcn_s_setprio(0);

        // mask in-place (exp2 domain); 4-way-partial max tree (v8)
        float pmx[4];
#pragma unroll
        for (int r2 = 0; r2 < 4; r2++) pmx[r2] = -3e38f;
        if (kb0 + 63 < qmin) {          // interior tile
#pragma unroll
            for (int tt = 0; tt < 2; tt++)
#pragma unroll
                for (int g = 0; g < 4; g++) {
                    float4 mb4 = *(const float4*)(sMB + kb0 + tt * 32 + 8 * g + 4 * half);
#pragma unroll
                    for (int r2 = 0; r2 < 4; r2++) {
                        float vv = sacc[tt][g * 4 + r2] + ((const float*)&mb4)[r2];
                        sacc[tt][g * 4 + r2] = vv;
                        pmx[r2] = fmaxf(pmx[r2], vv);
                    }
                }
        } else {
#pragma unroll
            for (int tt = 0; tt < 2; tt++)
#pragma unroll
                for (int g = 0; g < 4; g++) {
                    float4 mb4 = *(const float4*)(sMB + kb0 + tt * 32 + 8 * g + 4 * half);
#pragma unroll
                    for (int r2 = 0; r2 < 4; r2++) {
                        int sk = kb0 + tt * 32 + 8 * g + 4 * half + r2;
                        float vv = sacc[tt][g * 4 + r2] + ((const float*)&mb4)[r2];
                        vv = (sk > myq) ? -1e30f : vv;
                        sacc[tt][g * 4 + r2] = vv;
                        pmx[r2] = fmaxf(pmx[r2], vv);
                    }
                }
        }
        float mx = fmaxf(fmaxf(pmx[0], pmx[1]), fmaxf(pmx[2], pmx[3]));

        // online softmax (exp2 domain): 32 in-lane + 1 cross-half shuffle
        mx = fmaxf(mx, __shfl_xor(mx, 32, 64));
        float mnew = fmaxf(m_s, mx);
        // T13 defer-max: skip O-rescale when tile max grew <= 8 (P bounded by 2^8).
        if (__all(mx - m_s <= 8.0f)) mnew = m_s;
        float alpha = exp2f(m_s - mnew);
        // 4-way-partial sum tree (v8): depth 8 adds per partial instead of 32 serial
        float prs[4];
#pragma unroll
        for (int r2 = 0; r2 < 4; r2++) prs[r2] = 0.0f;
#pragma unroll
        for (int tt = 0; tt < 2; tt++)
#pragma unroll
            for (int c = 0; c < 16; c++) {
                float pe = exp2f(sacc[tt][c] - mnew);
                sacc[tt][c] = pe;
                prs[c & 3] += pe;
            }
        float rs = (prs[0] + prs[1]) + (prs[2] + prs[3]);
        l_s = l_s * alpha + rs;
        if (mnew > m_s) {
#pragma unroll
            for (int dt = 0; dt < 4; dt++) oacc[dt] *= alpha;
        }
        m_s = mnew;

        // PV: P B-fragments in-register via cross-half dword exchange
#pragma unroll
        for (int tt = 0; tt < 2; tt++) {
            unsigned w8[8];
#pragma unroll
            for (int i = 0; i < 8; i++)
                w8[i] = pack2(sacc[tt][2 * i], sacc[tt][2 * i + 1]);
#pragma unroll
            for (int s2 = 0; s2 < 2; s2++) {
                const int bse = 4 * s2;
                unsigned a0 = half ? w8[bse]     : w8[bse + 2];
                unsigned a1 = half ? w8[bse + 1] : w8[bse + 3];
                unsigned z0 = (unsigned)__shfl_xor((int)a0, 32, 64);
                unsigned z1 = (unsigned)__shfl_xor((int)a1, 32, 64);
                union { unsigned u[4]; bf16x8 vv; } pu;
                pu.u[0] = half ? z0 : w8[bse];
                pu.u[1] = half ? z1 : w8[bse + 1];
                pu.u[2] = half ? w8[bse + 2] : z0;
                pu.u[3] = half ? w8[bse + 3] : z1;
                bf16x8 pf = pu.vv;
                const int c = (tt * 2 + s2) * 2 + half;
                __builtin_amdgcn_s_setprio(1);
#pragma unroll
                for (int dt = 0; dt < 4; dt++) {
                    int row = dt * 32 + l31;
                    int x = c ^ swv;
                    bf16x8 vf = *(const bf16x8*)(sVb + row * 64 + x * 8);
                    oacc[dt] = MFMA32(vf, pf, oacc[dt]);
                }
                __builtin_amdgcn_s_setprio(0);
            }
        }
        __syncthreads();
    }

    // epilogue
    float lf = l_s + __shfl_xor(l_s, 32, 64);
    if (role == 0) {
        size_t slot = (size_t)(bh * 8 + (qa - 8)) * 2 + 0;
        float* op = Opart + slot * 16384 + (size_t)(w * 32 + l31) * 128;
#pragma unroll
        for (int dt = 0; dt < 4; dt++)
#pragma unroll
            for (int g = 0; g < 4; g++) {
                float4 o4 = make_float4(oacc[dt][g * 4 + 0], oacc[dt][g * 4 + 1],
                                        oacc[dt][g * 4 + 2], oacc[dt][g * 4 + 3]);
                *(float4*)(op + dt * 32 + 8 * g + 4 * half) = o4;
            }
        if (half == 0) {
            float* mp = mlpart + (slot * 128 + (w * 32 + l31)) * 2;
            mp[0] = m_s; mp[1] = lf;
        }
    } else {
        float inv = 1.0f / lf;
        size_t base = ((size_t)(b * 2048 + myq)) * 2048 + hh * 128;
#pragma unroll
        for (int dt = 0; dt < 4; dt++)
#pragma unroll
            for (int g = 0; g < 4; g++) {
                bf16x4 o4;
#pragma unroll
                for (int r2 = 0; r2 < 4; r2++) o4[r2] = (bf16)(oacc[dt][g * 4 + r2] * inv);
                *(bf16x4*)(O + base + dt * 32 + 8 * g + 4 * half) = o4;
            }
    }
}

// ---------------- combine: merge split-K partials for heavy q-tiles ----------------
__global__ void combine(const float* __restrict__ Opart, const float* __restrict__ mlpart,
                        bf16* __restrict__ attn) {
    int i = blockIdx.x * 256 + threadIdx.x;     // 1,048,576 quads
    int dq = (i & 31) * 4;
    int row = i >> 5;                            // (bh*8+ai)*128 + qloc
    int qloc = row & 127, ba = row >> 7;
    int ai = ba & 7, bh = ba >> 3;
    const float* mlA = mlpart + ((size_t)(ba * 2 + 0) * 128 + qloc) * 2;
    const float* mlB = mlpart + ((size_t)(ba * 2 + 1) * 128 + qloc) * 2;
    float mA = mlA[0], lA = mlA[1], mB = mlB[0], lB = mlB[1];
    float m = fmaxf(mA, mB);
    float wA = exp2f(mA - m), wB = exp2f(mB - m);
    float inv = 1.0f / (wA * lA + wB * lB);
    float4 oA = *(const float4*)(Opart + (size_t)(ba * 2 + 0) * 16384 + qloc * 128 + dq);
    float4 oB = *(const float4*)(Opart + (size_t)(ba * 2 + 1) * 16384 + qloc * 128 + dq);
    int q = (8 + ai) * 128 + qloc;
    int b = bh >> 4, hh = bh & 15;
    bf16x4 o4;
    o4[0] = (bf16)((wA * oA.x + wB * oB.x) * inv);
    o4[1] = (bf16)((wA * oA.y + wB * oB.y) * inv);
    o4[2] = (bf16)((wA * oA.z + wB * oB.z) * inv);
    o4[3] = (bf16)((wA * oA.w + wB * oB.w) * inv);
    *(bf16x4*)(attn + ((size_t)(b * 2048 + q)) * 2048 + hh * 128 + dq) = o4;
}

extern "C" void kernel_launch(void* const* d_in, const int* in_sizes, int n_in,
                              void* d_out, int out_size, void* d_ws, size_t ws_size,
                              hipStream_t stream) {
    const float* x     = (const float*)d_in[0];
    const int*   am    = (const int*)d_in[1];
    const float* qkvw  = (const float*)d_in[2];
    const float* qkvb  = (const float*)d_in[3];
    const float* outw  = (const float*)d_in[4];
    const float* outb  = (const float*)d_in[5];
    float* out = (float*)d_out;

    char* ws = (char*)d_ws;
    bf16*  xb    = (bf16*)(ws);                          // 16 MB  x bf16
    bf16*  wqkv  = (bf16*)(ws + (16ull << 20));          // 24 MB  qkv_w bf16
    bf16*  wout  = (bf16*)(ws + (40ull << 20));          //  8 MB  out_w bf16
    bf16*  qb    = (bf16*)(ws + (48ull << 20));          // 16 MB  q (pre-scaled /ln2)
    bf16*  kb    = (bf16*)(ws + (64ull << 20));          // 16 MB  k
    bf16*  vtb   = (bf16*)(ws + (80ull << 20));          // 16 MB  v^T
    bf16*  attn  = (bf16*)(ws + (96ull << 20));          // 16 MB  attn [4096,2048]
    float* cosT  = (float*)(ws + (112ull << 20));        //  1 MB
    float* sinT  = (float*)(ws + (113ull << 20));        //  1 MB
    float* mbias = (float*)(ws + (114ull << 20));        // 16 KB
    // split-K partials ALIAS xb/wqkv (dead after gemm1; stream order guarantees safety)
    float* Opart  = (float*)(ws);                        // 32 MB  [32bh][8a][2role][128q][128d]
    float* mlpart = (float*)(ws + (32ull << 20));        // 0.5 MB [.][.][.][128q][m,l]

    prep<<<13312, 256, 0, stream>>>(x, qkvw, outw, am, xb, wqkv, wout, cosT, sinT, mbias);

    gemm_bt<1><<<dim3(32, 48), 256, 0, stream>>>(
        xb, wqkv, qkvb, nullptr, qb, kb, vtb, cosT, sinT, 4096, 6144, 2048);

    fattn<<<dim3(512), 256, 0, stream>>>(qb, kb, vtb, mbias, attn, Opart, mlpart);

    combine<<<4096, 256, 0, stream>>>(Opart, mlpart, attn);

    gemm_bt<0><<<dim3(32, 16), 256, 0, stream>>>(
        attn, wout, outb, out, nullptr, nullptr, nullptr, nullptr, nullptr,
        4096, 2048, 2048);
}

// Round 7
// 378.837 us; speedup vs baseline: 1.2237x; 1.0216x over previous
//
#include <hip/hip_runtime.h>

typedef __bf16 bf16;
typedef __bf16 bf16x2 __attribute__((ext_vector_type(2)));
typedef __bf16 bf16x4 __attribute__((ext_vector_type(4)));
typedef __bf16 bf16x8 __attribute__((ext_vector_type(8)));
typedef float f32x4 __attribute__((ext_vector_type(4)));
typedef float f32x16 __attribute__((ext_vector_type(16)));

#define MFMA_BF16(a, b, c) __builtin_amdgcn_mfma_f32_16x16x32_bf16(a, b, c, 0, 0, 0)
#define MFMA32(a, b, c)    __builtin_amdgcn_mfma_f32_32x32x16_bf16(a, b, c, 0, 0, 0)

__device__ __forceinline__ void async16(const void* g, void* l) {
    __builtin_amdgcn_global_load_lds(
        (const __attribute__((address_space(1))) void*)g,
        (__attribute__((address_space(3))) void*)l,
        16, 0, 0);
}

__device__ __forceinline__ unsigned pack2(float a, float b) {
    bf16x2 t; t[0] = (bf16)a; t[1] = (bf16)b;
    return __builtin_bit_cast(unsigned, t);
}

// ---------------- prep: all fp32->bf16 converts + RoPE tables + mask, ONE dispatch ----------------
// r7: RoPE table deduped to S x 64 (d and d+64 share inv_freq) — half the trig,
// half the table bytes (1 MB total), better L2 residency for gemm1's epilogue.
__device__ __forceinline__ void cvt8_body(const float* __restrict__ in,
                                          bf16* __restrict__ out, int blk) {
    int i = (blk * 256 + (int)threadIdx.x) * 8;
    float4 a = *(const float4*)(in + i);
    float4 b = *(const float4*)(in + i + 4);
    bf16x8 o;
    o[0] = (bf16)a.x; o[1] = (bf16)a.y; o[2] = (bf16)a.z; o[3] = (bf16)a.w;
    o[4] = (bf16)b.x; o[5] = (bf16)b.y; o[6] = (bf16)b.z; o[7] = (bf16)b.w;
    *(bf16x8*)(out + i) = o;
}

__global__ void prep(const float* __restrict__ x, const float* __restrict__ qkvw,
                     const float* __restrict__ outw, const int* __restrict__ am,
                     bf16* __restrict__ xb, bf16* __restrict__ wqkv, bf16* __restrict__ wout,
                     float* __restrict__ cosT, float* __restrict__ sinT,
                     float* __restrict__ mbias) {
    int blk = blockIdx.x;
    if (blk < 4096)        cvt8_body(x,    xb,   blk);
    else if (blk < 10240)  cvt8_body(qkvw, wqkv, blk - 4096);
    else if (blk < 12288)  cvt8_body(outw, wout, blk - 10240);
    else {
        int i = (blk - 12288) * 256 + threadIdx.x;   // 0 .. 2048*64-1
        int s = i >> 6, fi = i & 63;
        float inv = exp2f(-(float)fi * (13.287712379549449f / 64.0f));
        float ang = (float)s * inv;
        cosT[i] = cosf(ang);
        sinT[i] = sinf(ang);
        if (i < 2 * 2048) mbias[i] = (am[i] == 0) ? -1.4427e30f : 0.0f;  // exp2 domain
    }
}

// ---------------- GEMM: C[M,N] = A[M,K] @ Bt[N,K]^T + bias ----------------
// (m97-structure, 821 TF measured round 0 on this problem; proven — do not touch.
//  256^2 restructure attempts r1/r4/r5 all landed at 455-553 TF. Closed.)
template <int EPI>
__global__ void __launch_bounds__(256, 2)
gemm_bt(const bf16* __restrict__ A, const bf16* __restrict__ Bt,
        const float* __restrict__ bias, float* __restrict__ Cf,
        bf16* __restrict__ qb, bf16* __restrict__ kb, bf16* __restrict__ vtb,
        const float* __restrict__ cosT, const float* __restrict__ sinT,
        int M, int N, int K) {
    __shared__ __align__(16) bf16 sA[128 * 64];
    __shared__ __align__(16) bf16 sB[128 * 64];
    const int tid  = threadIdx.x;
    const int lane = tid & 63;
    const int quad = lane >> 4, l15 = lane & 15;
    const int wid = tid >> 6, wm = wid >> 1, wn = wid & 1;
    const int bm = blockIdx.x, bn = blockIdx.y;

    f32x4 acc[4][4];
#pragma unroll
    for (int i = 0; i < 4; i++)
#pragma unroll
        for (int j = 0; j < 4; j++)
#pragma unroll
            for (int c = 0; c < 4; c++) acc[i][j][c] = 0.0f;

    const int r0 = tid >> 3, x0 = tid & 7;
    const int g0 = x0 ^ (r0 & 7);
    const bf16* pa = A  + (size_t)(bm * 128 + r0) * K + g0 * 8;
    const bf16* pb = Bt + (size_t)(bn * 128 + r0) * K + g0 * 8;
    bf16* la = sA + tid * 8;
    bf16* lb = sB + tid * 8;
    const size_t gstep = (size_t)32 * K;

    for (int k0 = 0; k0 < K; k0 += 64) {
#pragma unroll
        for (int i = 0; i < 4; i++) {
            async16(pa + i * gstep, la + i * 2048);
            async16(pb + i * gstep, lb + i * 2048);
        }
        pa += 64; pb += 64;
        __syncthreads();
#pragma unroll
        for (int ks = 0; ks < 2; ks++) {
            bf16x8 af[4], bfr[4];
#pragma unroll
            for (int i = 0; i < 4; i++) {
                int r = wm * 64 + i * 16 + l15;
                int x = (ks * 4 + quad) ^ (r & 7);
                af[i] = *(const bf16x8*)(sA + r * 64 + x * 8);
            }
#pragma unroll
            for (int i = 0; i < 4; i++) {
                int r = wn * 64 + i * 16 + l15;
                int x = (ks * 4 + quad) ^ (r & 7);
                bfr[i] = *(const bf16x8*)(sB + r * 64 + x * 8);
            }
#pragma unroll
            for (int mi = 0; mi < 4; mi++)
#pragma unroll
                for (int ni = 0; ni < 4; ni++)
                    acc[mi][ni] = MFMA_BF16(af[mi], bfr[ni], acc[mi][ni]);
        }
        __syncthreads();
    }

    if (EPI == 0) {
#pragma unroll
        for (int mi = 0; mi < 4; mi++)
#pragma unroll
            for (int ni = 0; ni < 4; ni++) {
                int row0 = bm * 128 + wm * 64 + mi * 16 + quad * 4;
                int col  = bn * 128 + wn * 64 + ni * 16 + l15;
                float bv = bias[col];
#pragma unroll
                for (int r = 0; r < 4; r++)
                    Cf[(size_t)(row0 + r) * N + col] = acc[mi][ni][r] + bv;
            }
    } else {
#pragma unroll
        for (int mi = 0; mi < 4; mi++)
#pragma unroll
            for (int ni = 0; ni < 4; ni++) {
                int col   = bn * 128 + wn * 64 + ni * 16 + l15;
                int which = col >> 11;
                int hcol  = col & 2047;
                int h = hcol >> 7, d = hcol & 127;
                float bv = bias[col];
#pragma unroll
                for (int r = 0; r < 4; r++) {
                    int row = bm * 128 + wm * 64 + mi * 16 + quad * 4 + r;
                    int b = row >> 11, s = row & 2047;
                    float v  = acc[mi][ni][r] + bv;
                    float vp = __shfl_xor(v, 1, 64);   // partner column d^1
                    float ov = v;
                    if (which < 2) {
                        float c  = cosT[(s << 6) + (d & 63)];   // S x 64 deduped table
                        float sn = sinT[(s << 6) + (d & 63)];
                        ov = v * c + ((d & 1) ? vp : -vp) * sn;
                    }
                    // q pre-scale: 1/sqrt(128)/ln2 (exp2-domain softmax)
                    if (which == 0) ov *= 0.12751743f;
                    size_t bh = (size_t)(b * 16 + h);
                    if (which == 0)      qb[(bh * 2048 + s) * 128 + d] = (bf16)ov;
                    else if (which == 1) kb[(bh * 2048 + s) * 128 + d] = (bf16)ov;
                    else                 vtb[(bh * 128 + d) * 2048 + s] = (bf16)ov;
                }
            }
    }
}

// ---------------- Flash attention v9: round-0 structure + tree-ILP softmax ONLY ----------------
// r6 lesson: setprio/defer-max/LDS-mbias bundle was a net ~9 µs REGRESSION on this
// 4-warp barrier-lockstep block structure (m190 regime: setprio hurts lockstep).
// Reverted to the verified round-0 code. Sole change: the per-tile 32-deep serial
// max/sum dependency chains -> 4-way partial trees (pure reassociation; max exact).
// Grid 512 1-D: id -> bh = id&31, v = id>>5, p = v>>1, role = v&1.
// Pair (heavy qt a=15-p [nkt=32-2p], light qt p [nkt=2p+2]); 34 tiles split:
//   role 0: qt=a, tiles [0,17)            -> partial slot (bh,a,0)
//   role 1: qt=a, tiles [17,32-2p)        -> partial slot (bh,a,1)
//           then qt=p, tiles [0,2p+2)     -> direct write (normalized)
// Partials: unnormalized O^T (fp32) + (m,l) per q-row; merged by combine().
__global__ void __launch_bounds__(256, 2)
fattn(const bf16* __restrict__ Q, const bf16* __restrict__ Kg,
      const bf16* __restrict__ Vt, const float* __restrict__ mbias,
      bf16* __restrict__ O, float* __restrict__ Opart, float* __restrict__ mlpart) {
    __shared__ __align__(16) bf16 sK[2][64 * 128];   // [buf][key][d]
    __shared__ __align__(16) bf16 sV[2][128 * 64];   // [buf][d][key]
    const int tid = threadIdx.x, lane = tid & 63, w = tid >> 6;
    const int l31 = lane & 31, half = lane >> 5;
    const int id = (int)blockIdx.x;
    const int bh = id & 31, v = id >> 5;
    const int p = v >> 1, role = v & 1;
    const int qa = 15 - p;                 // heavy q-tile
    const int n1 = role ? (15 - 2 * p) : 17;   // first-segment tile count

    const bf16* Qb  = Q  + (size_t)bh * 2048 * 128;
    const bf16* Kbh = Kg + (size_t)bh * 2048 * 128;
    const bf16* Vbh = Vt + (size_t)bh * 128 * 2048;
    const int b = bh >> 4, hh = bh & 15;
    const float* mbb = mbias + b * 2048;

    // per-lane read swizzles (full-bank coverage)
    const int swk = (l31 & 15) ^ (l31 >> 4);
    const int swv = (l31 & 7) ^ ((l31 >> 3) & 3);
    // staging indices
    const int rk = tid >> 4, xk = tid & 15, gkb = xk ^ rk;   // ^ (i&1) per i
    const int rv = tid >> 3, xv = tid & 7;
    const int gv = xv ^ (rv & 7) ^ ((rv >> 3) & 3);

    // tile t in [0,17) -> key-tile index
    auto KT = [&](int t) { return role ? (t < n1 ? 17 + t : t - n1) : t; };

    int qt = qa;
    int myq  = qt * 128 + w * 32 + l31;
    int qmin = qt * 128 + w * 32;

    bf16x8 qf[8];
#pragma unroll
    for (int kq = 0; kq < 8; kq++)
        qf[kq] = *(const bf16x8*)(Qb + (size_t)myq * 128 + kq * 16 + half * 8);

    f32x16 oacc[4];
#pragma unroll
    for (int dt = 0; dt < 4; dt++)
#pragma unroll
        for (int c = 0; c < 16; c++) oacc[dt][c] = 0.0f;
    float m_s = -3e38f, l_s = 0.0f;

    // stage tile 0 into buffer 0
    {
        int kb0 = KT(0) * 64;
#pragma unroll
        for (int i = 0; i < 4; i++) {
            async16(Kbh + (size_t)(kb0 + rk + i * 16) * 128 + (gkb ^ (i & 1)) * 8,
                    &sK[0][(i * 256 + tid) * 8]);
            async16(Vbh + (size_t)(rv + i * 32) * 2048 + kb0 + gv * 8,
                    &sV[0][(i * 256 + tid) * 8]);
        }
    }
    __syncthreads();

    for (int t = 0; t < 17; t++) {
        // segment boundary (role 1 only): finalize heavy partial, switch to light qt
        if (role && t == n1) {
            float lf = l_s + __shfl_xor(l_s, 32, 64);
            size_t slot = (size_t)(bh * 8 + (qa - 8)) * 2 + 1;
            float* op = Opart + slot * 16384 + (size_t)(w * 32 + l31) * 128;
#pragma unroll
            for (int dt = 0; dt < 4; dt++)
#pragma unroll
                for (int g = 0; g < 4; g++) {
                    float4 o4 = make_float4(oacc[dt][g * 4 + 0], oacc[dt][g * 4 + 1],
                                            oacc[dt][g * 4 + 2], oacc[dt][g * 4 + 3]);
                    *(float4*)(op + dt * 32 + 8 * g + 4 * half) = o4;
                }
            if (half == 0) {
                float* mp = mlpart + (slot * 128 + (w * 32 + l31)) * 2;
                mp[0] = m_s; mp[1] = lf;
            }
#pragma unroll
            for (int dt = 0; dt < 4; dt++)
#pragma unroll
                for (int c = 0; c < 16; c++) oacc[dt][c] = 0.0f;
            m_s = -3e38f; l_s = 0.0f;
            qt = p;   // light q-tile
            myq  = qt * 128 + w * 32 + l31;
            qmin = qt * 128 + w * 32;
#pragma unroll
            for (int kq = 0; kq < 8; kq++)
                qf[kq] = *(const bf16x8*)(Qb + (size_t)myq * 128 + kq * 16 + half * 8);
        }

        const int kb0 = KT(t) * 64;
        const int buf = t & 1;
        if (t + 1 < 17) {
            const int nb0 = KT(t + 1) * 64;
#pragma unroll
            for (int i = 0; i < 4; i++) {
                async16(Kbh + (size_t)(nb0 + rk + i * 16) * 128 + (gkb ^ (i & 1)) * 8,
                        &sK[buf ^ 1][(i * 256 + tid) * 8]);
                async16(Vbh + (size_t)(rv + i * 32) * 2048 + nb0 + gv * 8,
                        &sV[buf ^ 1][(i * 256 + tid) * 8]);
            }
        }
        const bf16* sKb = sK[buf];
        const bf16* sVb = sV[buf];

        // S^T: rows = keys (2 tiles of 32), col = query
        f32x16 sacc[2];
#pragma unroll
        for (int tt = 0; tt < 2; tt++)
#pragma unroll
            for (int c = 0; c < 16; c++) sacc[tt][c] = 0.0f;
#pragma unroll
        for (int kq = 0; kq < 8; kq++) {
#pragma unroll
            for (int tt = 0; tt < 2; tt++) {
                int row = tt * 32 + l31;
                int x = (kq * 2 + half) ^ swk;
                bf16x8 kf = *(const bf16x8*)(sKb + row * 128 + x * 8);
                sacc[tt] = MFMA32(kf, qf[kq], sacc[tt]);
            }
        }

        // mask in-place (exp2 domain); 4-way-partial max tree
        float pmx[4];
#pragma unroll
        for (int r2 = 0; r2 < 4; r2++) pmx[r2] = -3e38f;
        if (kb0 + 63 < qmin) {          // interior tile
#pragma unroll
            for (int tt = 0; tt < 2; tt++)
#pragma unroll
                for (int g = 0; g < 4; g++) {
                    float4 mb4 = *(const float4*)(mbb + kb0 + tt * 32 + 8 * g + 4 * half);
#pragma unroll
                    for (int r2 = 0; r2 < 4; r2++) {
                        float vv = sacc[tt][g * 4 + r2] + ((const float*)&mb4)[r2];
                        sacc[tt][g * 4 + r2] = vv;
                        pmx[r2] = fmaxf(pmx[r2], vv);
                    }
                }
        } else {
#pragma unroll
            for (int tt = 0; tt < 2; tt++)
#pragma unroll
                for (int g = 0; g < 4; g++) {
                    float4 mb4 = *(const float4*)(mbb + kb0 + tt * 32 + 8 * g + 4 * half);
#pragma unroll
                    for (int r2 = 0; r2 < 4; r2++) {
                        int sk = kb0 + tt * 32 + 8 * g + 4 * half + r2;
                        float vv = sacc[tt][g * 4 + r2] + ((const float*)&mb4)[r2];
                        vv = (sk > myq) ? -1e30f : vv;
                        sacc[tt][g * 4 + r2] = vv;
                        pmx[r2] = fmaxf(pmx[r2], vv);
                    }
                }
        }
        float mx = fmaxf(fmaxf(pmx[0], pmx[1]), fmaxf(pmx[2], pmx[3]));

        // online softmax (exp2 domain): 32 in-lane + 1 cross-half shuffle
        mx = fmaxf(mx, __shfl_xor(mx, 32, 64));
        float mnew  = fmaxf(m_s, mx);
        float alpha = exp2f(m_s - mnew);
        // 4-way-partial sum tree
        float prs[4];
#pragma unroll
        for (int r2 = 0; r2 < 4; r2++) prs[r2] = 0.0f;
#pragma unroll
        for (int tt = 0; tt < 2; tt++)
#pragma unroll
            for (int c = 0; c < 16; c++) {
                float pe = exp2f(sacc[tt][c] - mnew);
                sacc[tt][c] = pe;
                prs[c & 3] += pe;
            }
        float rs = (prs[0] + prs[1]) + (prs[2] + prs[3]);
        l_s = l_s * alpha + rs;
        m_s = mnew;
#pragma unroll
        for (int dt = 0; dt < 4; dt++) oacc[dt] *= alpha;

        // PV: P B-fragments in-register via cross-half dword exchange
#pragma unroll
        for (int tt = 0; tt < 2; tt++) {
            unsigned w8[8];
#pragma unroll
            for (int i = 0; i < 8; i++)
                w8[i] = pack2(sacc[tt][2 * i], sacc[tt][2 * i + 1]);
#pragma unroll
            for (int s2 = 0; s2 < 2; s2++) {
                const int bse = 4 * s2;
                unsigned a0 = half ? w8[bse]     : w8[bse + 2];
                unsigned a1 = half ? w8[bse + 1] : w8[bse + 3];
                unsigned z0 = (unsigned)__shfl_xor((int)a0, 32, 64);
                unsigned z1 = (unsigned)__shfl_xor((int)a1, 32, 64);
                union { unsigned u[4]; bf16x8 vv; } pu;
                pu.u[0] = half ? z0 : w8[bse];
                pu.u[1] = half ? z1 : w8[bse + 1];
                pu.u[2] = half ? w8[bse + 2] : z0;
                pu.u[3] = half ? w8[bse + 3] : z1;
                bf16x8 pf = pu.vv;
                const int c = (tt * 2 + s2) * 2 + half;
#pragma unroll
                for (int dt = 0; dt < 4; dt++) {
                    int row = dt * 32 + l31;
                    int x = c ^ swv;
                    bf16x8 vf = *(const bf16x8*)(sVb + row * 64 + x * 8);
                    oacc[dt] = MFMA32(vf, pf, oacc[dt]);
                }
            }
        }
        __syncthreads();
    }

    // epilogue
    float lf = l_s + __shfl_xor(l_s, 32, 64);
    if (role == 0) {
        size_t slot = (size_t)(bh * 8 + (qa - 8)) * 2 + 0;
        float* op = Opart + slot * 16384 + (size_t)(w * 32 + l31) * 128;
#pragma unroll
        for (int dt = 0; dt < 4; dt++)
#pragma unroll
            for (int g = 0; g < 4; g++) {
                float4 o4 = make_float4(oacc[dt][g * 4 + 0], oacc[dt][g * 4 + 1],
                                        oacc[dt][g * 4 + 2], oacc[dt][g * 4 + 3]);
                *(float4*)(op + dt * 32 + 8 * g + 4 * half) = o4;
            }
        if (half == 0) {
            float* mp = mlpart + (slot * 128 + (w * 32 + l31)) * 2;
            mp[0] = m_s; mp[1] = lf;
        }
    } else {
        float inv = 1.0f / lf;
        size_t base = ((size_t)(b * 2048 + myq)) * 2048 + hh * 128;
#pragma unroll
        for (int dt = 0; dt < 4; dt++)
#pragma unroll
            for (int g = 0; g < 4; g++) {
                bf16x4 o4;
#pragma unroll
                for (int r2 = 0; r2 < 4; r2++) o4[r2] = (bf16)(oacc[dt][g * 4 + r2] * inv);
                *(bf16x4*)(O + base + dt * 32 + 8 * g + 4 * half) = o4;
            }
    }
}

// ---------------- combine: merge split-K partials for heavy q-tiles ----------------
__global__ void combine(const float* __restrict__ Opart, const float* __restrict__ mlpart,
                        bf16* __restrict__ attn) {
    int i = blockIdx.x * 256 + threadIdx.x;     // 1,048,576 quads
    int dq = (i & 31) * 4;
    int row = i >> 5;                            // (bh*8+ai)*128 + qloc
    int qloc = row & 127, ba = row >> 7;
    int ai = ba & 7, bh = ba >> 3;
    const float* mlA = mlpart + ((size_t)(ba * 2 + 0) * 128 + qloc) * 2;
    const float* mlB = mlpart + ((size_t)(ba * 2 + 1) * 128 + qloc) * 2;
    float mA = mlA[0], lA = mlA[1], mB = mlB[0], lB = mlB[1];
    float m = fmaxf(mA, mB);
    float wA = exp2f(mA - m), wB = exp2f(mB - m);
    float inv = 1.0f / (wA * lA + wB * lB);
    float4 oA = *(const float4*)(Opart + (size_t)(ba * 2 + 0) * 16384 + qloc * 128 + dq);
    float4 oB = *(const float4*)(Opart + (size_t)(ba * 2 + 1) * 16384 + qloc * 128 + dq);
    int q = (8 + ai) * 128 + qloc;
    int b = bh >> 4, hh = bh & 15;
    bf16x4 o4;
    o4[0] = (bf16)((wA * oA.x + wB * oB.x) * inv);
    o4[1] = (bf16)((wA * oA.y + wB * oB.y) * inv);
    o4[2] = (bf16)((wA * oA.z + wB * oB.z) * inv);
    o4[3] = (bf16)((wA * oA.w + wB * oB.w) * inv);
    *(bf16x4*)(attn + ((size_t)(b * 2048 + q)) * 2048 + hh * 128 + dq) = o4;
}

extern "C" void kernel_launch(void* const* d_in, const int* in_sizes, int n_in,
                              void* d_out, int out_size, void* d_ws, size_t ws_size,
                              hipStream_t stream) {
    const float* x     = (const float*)d_in[0];
    const int*   am    = (const int*)d_in[1];
    const float* qkvw  = (const float*)d_in[2];
    const float* qkvb  = (const float*)d_in[3];
    const float* outw  = (const float*)d_in[4];
    const float* outb  = (const float*)d_in[5];
    float* out = (float*)d_out;

    char* ws = (char*)d_ws;
    bf16*  xb    = (bf16*)(ws);                          // 16 MB  x bf16
    bf16*  wqkv  = (bf16*)(ws + (16ull << 20));          // 24 MB  qkv_w bf16
    bf16*  wout  = (bf16*)(ws + (40ull << 20));          //  8 MB  out_w bf16
    bf16*  qb    = (bf16*)(ws + (48ull << 20));          // 16 MB  q (pre-scaled /ln2)
    bf16*  kb    = (bf16*)(ws + (64ull << 20));          // 16 MB  k
    bf16*  vtb   = (bf16*)(ws + (80ull << 20));          // 16 MB  v^T
    bf16*  attn  = (bf16*)(ws + (96ull << 20));          // 16 MB  attn [4096,2048]
    float* cosT  = (float*)(ws + (112ull << 20));        //  0.5 MB (S x 64)
    float* sinT  = (float*)(ws + (113ull << 20));        //  0.5 MB (S x 64)
    float* mbias = (float*)(ws + (114ull << 20));        // 16 KB
    // split-K partials ALIAS xb/wqkv (dead after gemm1; stream order guarantees safety)
    float* Opart  = (float*)(ws);                        // 32 MB  [32bh][8a][2role][128q][128d]
    float* mlpart = (float*)(ws + (32ull << 20));        // 0.5 MB [.][.][.][128q][m,l]

    prep<<<12800, 256, 0, stream>>>(x, qkvw, outw, am, xb, wqkv, wout, cosT, sinT, mbias);

    gemm_bt<1><<<dim3(32, 48), 256, 0, stream>>>(
        xb, wqkv, qkvb, nullptr, qb, kb, vtb, cosT, sinT, 4096, 6144, 2048);

    fattn<<<dim3(512), 256, 0, stream>>>(qb, kb, vtb, mbias, attn, Opart, mlpart);

    combine<<<4096, 256, 0, stream>>>(Opart, mlpart, attn);

    gemm_bt<0><<<dim3(32, 16), 256, 0, stream>>>(
        attn, wout, outb, out, nullptr, nullptr, nullptr, nullptr, nullptr,
        4096, 2048, 2048);
}